// Round 6
// baseline (273.413 us; speedup 1.0000x reference)
//
#include <hip/hip_runtime.h>
#include <math.h>

#define N_NODES 20000
#define N_EDGES 320000
#define DIM 64
#define SUB 16
#define NRBF 8
#define NB 5
#define LAYERS 3
#define FCIN (NRBF*SUB*NB + SUB)   // 656
#define KPAD 672                   // 21 * 32
#define NKK 21
#define HD 64
#define CUTOFF 5.0f
#define LOG2F_ 0.69314718055994530942f

typedef __attribute__((ext_vector_type(8))) short short8;
typedef __attribute__((ext_vector_type(4))) float float4v;
typedef __attribute__((ext_vector_type(2))) float float2v;
typedef __attribute__((ext_vector_type(2))) unsigned int uint2v;

__device__ __forceinline__ float ssp(float x) {
    float sp = fmaxf(x, 0.0f) + log1pf(expf(-fabsf(x)));
    return sp - LOG2F_;
}

__device__ __forceinline__ unsigned short f2bf(float x) {
    unsigned int u = __float_as_uint(x);
    unsigned int r = (u + 0x7FFFu + ((u >> 16) & 1u)) >> 16;
    return (unsigned short)r;
}
__device__ __forceinline__ float bf2f(unsigned short s) {
    unsigned int u = ((unsigned int)s) << 16;
    return __uint_as_float(u);
}

// --- one-time kernels -------------------------------------------------------

__global__ void k_rowptr(const int* __restrict__ esrc, int* __restrict__ rowptr) {
    int n = blockIdx.x * blockDim.x + threadIdx.x;
    if (n > N_NODES) return;
    int a = 0, b = N_EDGES;
    while (a < b) { int m = (a + b) >> 1; if (esrc[m] < n) a = m + 1; else b = m; }
    rowptr[n] = a;
}

// uf[e][g*12+j] = sw[e] * rb[r] * bo[b]  (fp32), p=g+4j, r=p/5, b=p%5; j=10,11 pad=0
__global__ void k_u(const float* __restrict__ dist, const float* __restrict__ sw,
                    const float* __restrict__ bo, float* __restrict__ uf) {
    int i = blockIdx.x * blockDim.x + threadIdx.x;
    if (i >= N_EDGES * 48) return;
    int e = i / 48, t = i - e * 48;
    int g = t / 12, j = t - g * 12;
    float v = 0.0f;
    if (j < 10) {
        int p = g + 4 * j;
        int r = p / 5, b = p - r * 5;
        float mu = (CUTOFF / (NRBF - 1)) * (float)r;
        float inv_sigma = (float)NRBF / CUTOFF;
        float z = (dist[e] - mu) * inv_sigma;
        v = sw[e] * expf(-0.5f * z * z) * bo[e * NB + b];
    }
    uf[i] = v;
}

// Pack weights into MFMA B-fragment order (bf16). Same layout as round 3.
__global__ void k_packw(const float* __restrict__ w0, const float* __restrict__ w1,
                        const float* __restrict__ w2,
                        short* __restrict__ w0f, short* __restrict__ w1f,
                        short* __restrict__ w2f) {
    int i = blockIdx.x * blockDim.x + threadIdx.x;
    const int SZ0 = LAYERS * NKK * 4 * 64 * 8;       // 129024
    const int SZ12 = LAYERS * 2 * 4 * 64 * 8;        // 12288
    if (i < SZ0) {
        int j = i & 7, t = i >> 3;
        int lane = t & 63; t >>= 6;
        int nf = t & 3; t >>= 2;
        int kk = t % NKK, l = t / NKK;
        int kp = kk * 32 + (lane >> 4) * 8 + j;
        int col = nf * 16 + (lane & 15);
        float v = 0.0f;
        if (kp < FCIN) {
            int orig;
            if (kp < 640) {
                int j10 = kp >> 6, rem = kp & 63, g = rem >> 4, s = rem & 15;
                int p = g + 4 * j10;
                orig = (p / 5) * 80 + s * 5 + (p - 5 * (p / 5));
            } else orig = kp;
            v = w0[((size_t)l * FCIN + orig) * HD + col];
        }
        w0f[i] = (short)f2bf(v);
        return;
    }
    i -= SZ0;
    if (i < 2 * SZ12) {
        const float* W = (i < SZ12) ? w1 : w2;
        short* Wf = (i < SZ12) ? w1f : w2f;
        int ii = (i < SZ12) ? i : i - SZ12;
        int j = ii & 7, t = ii >> 3;
        int lane = t & 63; t >>= 6;
        int nf = t & 3; t >>= 2;
        int kk = t & 1, l = t >> 1;
        int kp = kk * 32 + (lane >> 4) * 8 + j;
        int col = nf * 16 + (lane & 15);
        Wf[ii] = (short)f2bf(W[((size_t)l * HD + kp) * HD + col]);
    }
}

__global__ void k_init_xi(const int* __restrict__ species,
                          const float* __restrict__ Wsp,
                          float* __restrict__ xi) {
    int i = blockIdx.x * blockDim.x + threadIdx.x;
    if (i >= N_NODES * DIM) return;
    int n = i >> 6, d = i & 63;
    xi[i] = Wsp[species[n] * DIM + d];
}

// --- per-layer kernels ------------------------------------------------------

// h = xi @ W_sm[l] + b_sm[l]; si fp32, mi bf16 (feeds the edge gather)
__global__ void k_h(const float* __restrict__ xi,
                    const float* __restrict__ Wsm, const float* __restrict__ bsm,
                    float* __restrict__ si, unsigned short* __restrict__ mi16, int l) {
    int i = blockIdx.x * blockDim.x + threadIdx.x;
    if (i >= N_NODES * 2 * SUB) return;
    int n = i >> 5, j = i & 31;
    const float* W = Wsm + l * DIM * 2 * SUB;
    const float* xr = xi + n * DIM;
    float v = bsm[l * 2 * SUB + j];
    #pragma unroll
    for (int d = 0; d < DIM; ++d) v = fmaf(xr[d], W[d * 2 * SUB + j], v);
    if (j < SUB) si[n * SUB + j] = v;
    else         mi16[n * SUB + (j - SUB)] = f2bf(v);
}

// Edge-parallel gather: medge[e][0:16] = mi16[edst[e]][0:16]. uint2 = 4 bf16/lane.
__global__ void k_gather(const int* __restrict__ edst,
                         const unsigned short* __restrict__ mi16,
                         unsigned short* __restrict__ medge) {
    int i = blockIdx.x * blockDim.x + threadIdx.x;   // i < E*4
    if (i >= N_EDGES * 4) return;
    int e = i >> 2, q = i & 3;
    int dst = edst[e];
    ((uint2v*)medge)[i] = ((const uint2v*)mi16)[dst * 4 + q];
}

// Per-edge aggregation body: 3 vector loads of fp32 u + 1 bf16 medge, 10 fma.
#define AGG_BODY(e, A)                                                        \
    {                                                                         \
        const float* up = uf + (size_t)(e) * 48 + g * 12;                     \
        float4v ua = *(const float4v*)(up);                                   \
        float4v ub = *(const float4v*)(up + 4);                               \
        float2v uc = *(const float2v*)(up + 8);                               \
        float m = bf2f(medge[(size_t)(e) * 16 + s]);                          \
        A##0 = fmaf(ua.x, m, A##0); A##1 = fmaf(ua.y, m, A##1);               \
        A##2 = fmaf(ua.z, m, A##2); A##3 = fmaf(ua.w, m, A##3);               \
        A##4 = fmaf(ub.x, m, A##4); A##5 = fmaf(ub.y, m, A##5);               \
        A##6 = fmaf(ub.z, m, A##6); A##7 = fmaf(ub.w, m, A##7);               \
        A##8 = fmaf(uc.x, m, A##8); A##9 = fmaf(uc.y, m, A##9);               \
    }

#define AGG_STORE(node, A)                                                    \
    {                                                                         \
        unsigned short* cp = cat + (size_t)(node) * KPAD;                     \
        cp[0*64+lane]=f2bf(A##0); cp[1*64+lane]=f2bf(A##1);                   \
        cp[2*64+lane]=f2bf(A##2); cp[3*64+lane]=f2bf(A##3);                   \
        cp[4*64+lane]=f2bf(A##4); cp[5*64+lane]=f2bf(A##5);                   \
        cp[6*64+lane]=f2bf(A##6); cp[7*64+lane]=f2bf(A##7);                   \
        cp[8*64+lane]=f2bf(A##8); cp[9*64+lane]=f2bf(A##9);                   \
        if (lane < SUB)      cp[640 + lane] = f2bf(si[(size_t)(node) * SUB + lane]); \
        else if (lane < 32)  cp[640 + lane] = 0;                              \
    }

// Aggregation: each wave owns TWO adjacent nodes (interleaved edge streams for
// ILP). Lane (g=lane>>4, s=lane&15); acc[j] = sum_e uf[e][g*12+j]*medge[e][s].
// Block = 4 waves = 8 nodes; grid N/8.
__global__ __launch_bounds__(256) void k_agg(
    const int* __restrict__ rowptr,
    const float* __restrict__ uf,
    const unsigned short* __restrict__ medge,
    const float* __restrict__ si,
    unsigned short* __restrict__ cat)
{
    const int lane = threadIdx.x & 63;
    const int w = threadIdx.x >> 6;
    const int nA = blockIdx.x * 8 + 2 * w;     // nodes nA, nA+1
    const int s = lane & 15;
    const int g = lane >> 4;

    const int e0 = rowptr[nA], e1 = rowptr[nA + 1], e2 = rowptr[nA + 2];
    const int lenA = e1 - e0, lenB = e2 - e1;
    const int common = lenA < lenB ? lenA : lenB;

    float a0=0,a1=0,a2=0,a3=0,a4=0,a5=0,a6=0,a7=0,a8=0,a9=0;
    float c0=0,c1=0,c2=0,c3=0,c4=0,c5=0,c6=0,c7=0,c8=0,c9=0;

    // interleaved portion: two independent load+FMA chains
    for (int i = 0; i < common; ++i) {
        AGG_BODY(e0 + i, a)
        AGG_BODY(e1 + i, c)
    }
    // tails
    for (int e = e0 + common; e < e1; ++e) AGG_BODY(e, a)
    for (int e = e1 + common; e < e2; ++e) AGG_BODY(e, c)

    AGG_STORE(nA, a)
    AGG_STORE(nA + 1, c)
}

// Fused MFMA MLP: 16 nodes/block, 4 waves; wave w owns output cols [16w,16w+16),
// full K. fc0 uses two independent MFMA accumulator chains for ILP.
__global__ __launch_bounds__(256) void k_mlp(
    const unsigned short* __restrict__ cat,
    const short* __restrict__ w0f, const float* __restrict__ b0,
    const short* __restrict__ w1f, const float* __restrict__ b1,
    const short* __restrict__ w2f, const float* __restrict__ b2,
    float* __restrict__ xi, int l)
{
    __shared__ __align__(16) unsigned short h1[16][72];
    __shared__ __align__(16) unsigned short h2[16][72];
    const int lane = threadIdx.x & 63;
    const int w = threadIdx.x >> 6;
    const int n0 = blockIdx.x * 16;
    const int r = lane & 15, g = lane >> 4;

    // fc0: K=672, 21 MFMA steps split into 2 independent chains
    const short* Ap = (const short*)cat + (size_t)(n0 + r) * KPAD + g * 8;
    const short* Bp = w0f + ((size_t)l * NKK * 256 + w * 64 + lane) * 8;
    float bv = b0[l * HD + w * 16 + r];
    float4v accA = {bv, bv, bv, bv};
    float4v accB = {0.f, 0.f, 0.f, 0.f};
    #pragma unroll 5
    for (int kk = 0; kk < 20; kk += 2) {
        short8 aA = *(const short8*)(Ap + kk * 32);
        short8 bA = *(const short8*)(Bp + (size_t)kk * 2048);
        accA = __builtin_amdgcn_mfma_f32_16x16x32_bf16(aA, bA, accA, 0, 0, 0);
        short8 aB = *(const short8*)(Ap + (kk + 1) * 32);
        short8 bB = *(const short8*)(Bp + (size_t)(kk + 1) * 2048);
        accB = __builtin_amdgcn_mfma_f32_16x16x32_bf16(aB, bB, accB, 0, 0, 0);
    }
    {
        short8 a = *(const short8*)(Ap + 20 * 32);
        short8 b = *(const short8*)(Bp + (size_t)20 * 2048);
        accA = __builtin_amdgcn_mfma_f32_16x16x32_bf16(a, b, accA, 0, 0, 0);
    }
    #pragma unroll
    for (int i = 0; i < 4; ++i)
        h1[g * 4 + i][w * 16 + r] = f2bf(ssp(accA[i] + accB[i]));
    __syncthreads();

    // fc1
    bv = b1[l * HD + w * 16 + r];
    float4v acc1 = {bv, bv, bv, bv};
    #pragma unroll
    for (int kk = 0; kk < 2; ++kk) {
        short8 a = *(const short8*)((const short*)&h1[r][kk * 32 + g * 8]);
        short8 b = *(const short8*)(w1f + ((size_t)(l * 2 + kk) * 256 + w * 64 + lane) * 8);
        acc1 = __builtin_amdgcn_mfma_f32_16x16x32_bf16(a, b, acc1, 0, 0, 0);
    }
    #pragma unroll
    for (int i = 0; i < 4; ++i)
        h2[g * 4 + i][w * 16 + r] = f2bf(ssp(acc1[i]));
    __syncthreads();

    // fc2 + residual
    bv = b2[l * DIM + w * 16 + r];
    float4v acc2 = {bv, bv, bv, bv};
    #pragma unroll
    for (int kk = 0; kk < 2; ++kk) {
        short8 a = *(const short8*)((const short*)&h2[r][kk * 32 + g * 8]);
        short8 b = *(const short8*)(w2f + ((size_t)(l * 2 + kk) * 256 + w * 64 + lane) * 8);
        acc2 = __builtin_amdgcn_mfma_f32_16x16x32_bf16(a, b, acc2, 0, 0, 0);
    }
    #pragma unroll
    for (int i = 0; i < 4; ++i)
        xi[(size_t)(n0 + g * 4 + i) * DIM + w * 16 + r] += acc2[i];
}

extern "C" void kernel_launch(void* const* d_in, const int* in_sizes, int n_in,
                              void* d_out, int out_size, void* d_ws, size_t ws_size,
                              hipStream_t stream) {
    const int*   species = (const int*)  d_in[0];
    const int*   esrc    = (const int*)  d_in[1];
    const int*   edst    = (const int*)  d_in[2];
    const float* dist    = (const float*)d_in[3];
    const float* sw      = (const float*)d_in[4];
    const float* bo      = (const float*)d_in[5];
    const float* Wsp     = (const float*)d_in[6];
    const float* Wsm     = (const float*)d_in[7];
    const float* bsm     = (const float*)d_in[8];
    const float* w0      = (const float*)d_in[9];
    const float* b0      = (const float*)d_in[10];
    const float* w1      = (const float*)d_in[11];
    const float* b1      = (const float*)d_in[12];
    const float* w2      = (const float*)d_in[13];
    const float* b2      = (const float*)d_in[14];

    float* xi = (float*)d_out;   // N x 64 fp32, updated in place

    // ws layout: uf E*48 f32 | si N*16 f | mi16 N*16 ush | medge E*16 ush |
    //            cat N*672 ush | w0f | w1f | w2f | rowptr
    float*          uf    = (float*)d_ws;
    float*          si    = uf + (size_t)N_EDGES * 48;
    unsigned short* mi16  = (unsigned short*)(si + (size_t)N_NODES * SUB);
    unsigned short* medge = mi16 + (size_t)N_NODES * SUB;
    unsigned short* cat   = medge + (size_t)N_EDGES * 16;
    short* w0f = (short*)(cat + (size_t)N_NODES * KPAD);
    short* w1f = w0f + (size_t)LAYERS * NKK * 2048;
    short* w2f = w1f + (size_t)LAYERS * 2 * 2048;
    int* rowptr = (int*)(w2f + (size_t)LAYERS * 2 * 2048);

    k_rowptr<<<(N_NODES + 1 + 255) / 256, 256, 0, stream>>>(esrc, rowptr);
    k_u<<<(N_EDGES * 48 + 255) / 256, 256, 0, stream>>>(dist, sw, bo, uf);
    {
        int total = LAYERS * NKK * 2048 + 2 * LAYERS * 2 * 2048;
        k_packw<<<(total + 255) / 256, 256, 0, stream>>>(w0, w1, w2, w0f, w1f, w2f);
    }
    k_init_xi<<<(N_NODES * DIM + 255) / 256, 256, 0, stream>>>(species, Wsp, xi);

    for (int l = 0; l < LAYERS; ++l) {
        k_h<<<(N_NODES * 2 * SUB + 255) / 256, 256, 0, stream>>>(xi, Wsm, bsm, si, mi16, l);
        k_gather<<<(N_EDGES * 4 + 255) / 256, 256, 0, stream>>>(edst, mi16, medge);
        k_agg<<<N_NODES / 8, 256, 0, stream>>>(rowptr, uf, medge, si, cat);
        k_mlp<<<N_NODES / 16, 256, 0, stream>>>(cat, w0f, b0, w1f, b1, w2f, b2, xi, l);
    }
}

// Round 7
// 221.903 us; speedup vs baseline: 1.2321x; 1.2321x over previous
//
#include <hip/hip_runtime.h>
#include <math.h>

#define N_NODES 20000
#define N_EDGES 320000
#define DIM 64
#define SUB 16
#define NRBF 8
#define NB 5
#define LAYERS 3
#define FCIN (NRBF*SUB*NB + SUB)   // 656
#define KPAD 672                   // 21 * 32
#define NKK 21
#define HD 64
#define CUTOFF 5.0f
#define LOG2F_ 0.69314718055994530942f

typedef __attribute__((ext_vector_type(8))) short short8;
typedef __attribute__((ext_vector_type(4))) float float4v;
typedef __attribute__((ext_vector_type(4))) unsigned short ushort4v;
typedef __attribute__((ext_vector_type(2))) unsigned int uint2v;

__device__ __forceinline__ float ssp(float x) {
    float sp = fmaxf(x, 0.0f) + log1pf(expf(-fabsf(x)));
    return sp - LOG2F_;
}

__device__ __forceinline__ unsigned short f2bf(float x) {
    unsigned int u = __float_as_uint(x);
    unsigned int r = (u + 0x7FFFu + ((u >> 16) & 1u)) >> 16;
    return (unsigned short)r;
}
__device__ __forceinline__ float bf2f(unsigned short s) {
    unsigned int u = ((unsigned int)s) << 16;
    return __uint_as_float(u);
}

// --- one-time kernels -------------------------------------------------------

__global__ void k_rowptr(const int* __restrict__ esrc, int* __restrict__ rowptr) {
    int n = blockIdx.x * blockDim.x + threadIdx.x;
    if (n > N_NODES) return;
    int a = 0, b = N_EDGES;
    while (a < b) { int m = (a + b) >> 1; if (esrc[m] < n) a = m + 1; else b = m; }
    rowptr[n] = a;
}

// u16[e][g*12+j] = bf16( sw[e] * rb[r] * bo[b] ), p=g+4j, r=p/5, b=p%5; j=10,11 pad=0
__global__ void k_u(const float* __restrict__ dist, const float* __restrict__ sw,
                    const float* __restrict__ bo, unsigned short* __restrict__ u16) {
    int i = blockIdx.x * blockDim.x + threadIdx.x;
    if (i >= N_EDGES * 48) return;
    int e = i / 48, t = i - e * 48;
    int g = t / 12, j = t - g * 12;
    float v = 0.0f;
    if (j < 10) {
        int p = g + 4 * j;
        int r = p / 5, b = p - r * 5;
        float mu = (CUTOFF / (NRBF - 1)) * (float)r;
        float inv_sigma = (float)NRBF / CUTOFF;
        float z = (dist[e] - mu) * inv_sigma;
        v = sw[e] * expf(-0.5f * z * z) * bo[e * NB + b];
    }
    u16[i] = f2bf(v);
}

// Pack weights into MFMA B-fragment order (bf16). Same layout as round 3.
__global__ void k_packw(const float* __restrict__ w0, const float* __restrict__ w1,
                        const float* __restrict__ w2,
                        short* __restrict__ w0f, short* __restrict__ w1f,
                        short* __restrict__ w2f) {
    int i = blockIdx.x * blockDim.x + threadIdx.x;
    const int SZ0 = LAYERS * NKK * 4 * 64 * 8;       // 129024
    const int SZ12 = LAYERS * 2 * 4 * 64 * 8;        // 12288
    if (i < SZ0) {
        int j = i & 7, t = i >> 3;
        int lane = t & 63; t >>= 6;
        int nf = t & 3; t >>= 2;
        int kk = t % NKK, l = t / NKK;
        int kp = kk * 32 + (lane >> 4) * 8 + j;
        int col = nf * 16 + (lane & 15);
        float v = 0.0f;
        if (kp < FCIN) {
            int orig;
            if (kp < 640) {
                int j10 = kp >> 6, rem = kp & 63, g = rem >> 4, s = rem & 15;
                int p = g + 4 * j10;
                orig = (p / 5) * 80 + s * 5 + (p - 5 * (p / 5));
            } else orig = kp;
            v = w0[((size_t)l * FCIN + orig) * HD + col];
        }
        w0f[i] = (short)f2bf(v);
        return;
    }
    i -= SZ0;
    if (i < 2 * SZ12) {
        const float* W = (i < SZ12) ? w1 : w2;
        short* Wf = (i < SZ12) ? w1f : w2f;
        int ii = (i < SZ12) ? i : i - SZ12;
        int j = ii & 7, t = ii >> 3;
        int lane = t & 63; t >>= 6;
        int nf = t & 3; t >>= 2;
        int kk = t & 1, l = t >> 1;
        int kp = kk * 32 + (lane >> 4) * 8 + j;
        int col = nf * 16 + (lane & 15);
        Wf[ii] = (short)f2bf(W[((size_t)l * HD + kp) * HD + col]);
    }
}

__global__ void k_init_xi(const int* __restrict__ species,
                          const float* __restrict__ Wsp,
                          float* __restrict__ xi) {
    int i = blockIdx.x * blockDim.x + threadIdx.x;
    if (i >= N_NODES * DIM) return;
    int n = i >> 6, d = i & 63;
    xi[i] = Wsp[species[n] * DIM + d];
}

// --- per-layer kernels ------------------------------------------------------

// h = xi @ W_sm[l] + b_sm[l]; si fp32, mi bf16 (feeds the edge gather)
__global__ void k_h(const float* __restrict__ xi,
                    const float* __restrict__ Wsm, const float* __restrict__ bsm,
                    float* __restrict__ si, unsigned short* __restrict__ mi16, int l) {
    int i = blockIdx.x * blockDim.x + threadIdx.x;
    if (i >= N_NODES * 2 * SUB) return;
    int n = i >> 5, j = i & 31;
    const float* W = Wsm + l * DIM * 2 * SUB;
    const float* xr = xi + n * DIM;
    float v = bsm[l * 2 * SUB + j];
    #pragma unroll
    for (int d = 0; d < DIM; ++d) v = fmaf(xr[d], W[d * 2 * SUB + j], v);
    if (j < SUB) si[n * SUB + j] = v;
    else         mi16[n * SUB + (j - SUB)] = f2bf(v);
}

// Edge-parallel gather: medge[e][0:16] = mi16[edst[e]][0:16]. uint2 = 4 bf16/lane.
__global__ void k_gather(const int* __restrict__ edst,
                         const unsigned short* __restrict__ mi16,
                         unsigned short* __restrict__ medge) {
    int i = blockIdx.x * blockDim.x + threadIdx.x;   // i < E*4
    if (i >= N_EDGES * 4) return;
    int e = i >> 2, q = i & 3;
    int dst = edst[e];
    ((uint2v*)medge)[i] = ((const uint2v*)mi16)[dst * 4 + q];
}

// Aggregation: TWO waves per node, each a contiguous half of the node's edges;
// combine via LDS fp32 partials. Lane (g=lane>>4, s=lane&15):
// acc[j] = sum_e u16[e][g*12+j] * medge[e][s]. Simple affine loop -> compiler
// software-pipelines the loads. Block = 4 waves = 2 nodes; grid N/2.
__global__ __launch_bounds__(256) void k_agg(
    const int* __restrict__ rowptr,
    const unsigned short* __restrict__ u16,
    const unsigned short* __restrict__ medge,
    const float* __restrict__ si,
    unsigned short* __restrict__ cat)
{
    __shared__ float part[2][640];
    const int lane = threadIdx.x & 63;
    const int w = threadIdx.x >> 6;
    const int nl = w >> 1;            // node slot in block (0,1)
    const int half = w & 1;           // which half of the edge range
    const int n = blockIdx.x * 2 + nl;
    const int s = lane & 15;
    const int g = lane >> 4;

    const int lo0 = rowptr[n], hi0 = rowptr[n + 1];
    const int mid = lo0 + ((hi0 - lo0 + 1) >> 1);
    const int lo = half ? mid : lo0;
    const int hi = half ? hi0 : mid;

    float a0=0,a1=0,a2=0,a3=0,a4=0,a5=0,a6=0,a7=0,a8=0,a9=0;
    #pragma unroll 4
    for (int e = lo; e < hi; ++e) {
        float m = bf2f(medge[(size_t)e * 16 + s]);
        const unsigned short* up = u16 + (size_t)e * 48 + g * 12;
        ushort4v ua = *(const ushort4v*)(up);
        ushort4v ub = *(const ushort4v*)(up + 4);
        unsigned int uc = *(const unsigned int*)(up + 8);
        a0 = fmaf(bf2f(ua.x), m, a0); a1 = fmaf(bf2f(ua.y), m, a1);
        a2 = fmaf(bf2f(ua.z), m, a2); a3 = fmaf(bf2f(ua.w), m, a3);
        a4 = fmaf(bf2f(ub.x), m, a4); a5 = fmaf(bf2f(ub.y), m, a5);
        a6 = fmaf(bf2f(ub.z), m, a6); a7 = fmaf(bf2f(ub.w), m, a7);
        a8 = fmaf(bf2f((unsigned short)(uc & 0xFFFFu)), m, a8);
        a9 = fmaf(bf2f((unsigned short)(uc >> 16)), m, a9);
    }

    if (half) {
        float* pp = &part[nl][0];
        pp[0*64+lane]=a0; pp[1*64+lane]=a1; pp[2*64+lane]=a2; pp[3*64+lane]=a3;
        pp[4*64+lane]=a4; pp[5*64+lane]=a5; pp[6*64+lane]=a6; pp[7*64+lane]=a7;
        pp[8*64+lane]=a8; pp[9*64+lane]=a9;
    }
    __syncthreads();
    if (!half) {
        const float* pp = &part[nl][0];
        unsigned short* cp = cat + (size_t)n * KPAD;
        cp[0*64+lane]=f2bf(a0+pp[0*64+lane]); cp[1*64+lane]=f2bf(a1+pp[1*64+lane]);
        cp[2*64+lane]=f2bf(a2+pp[2*64+lane]); cp[3*64+lane]=f2bf(a3+pp[3*64+lane]);
        cp[4*64+lane]=f2bf(a4+pp[4*64+lane]); cp[5*64+lane]=f2bf(a5+pp[5*64+lane]);
        cp[6*64+lane]=f2bf(a6+pp[6*64+lane]); cp[7*64+lane]=f2bf(a7+pp[7*64+lane]);
        cp[8*64+lane]=f2bf(a8+pp[8*64+lane]); cp[9*64+lane]=f2bf(a9+pp[9*64+lane]);
        if (lane < SUB)      cp[640 + lane] = f2bf(si[(size_t)n * SUB + lane]);
        else if (lane < 32)  cp[640 + lane] = 0;   // pad cols 656..671
    }
}

// Fused MFMA MLP: 16 nodes/block, 4 waves; wave w owns output cols [16w,16w+16),
// full K. fc0 uses two independent MFMA accumulator chains for ILP.
__global__ __launch_bounds__(256) void k_mlp(
    const unsigned short* __restrict__ cat,
    const short* __restrict__ w0f, const float* __restrict__ b0,
    const short* __restrict__ w1f, const float* __restrict__ b1,
    const short* __restrict__ w2f, const float* __restrict__ b2,
    float* __restrict__ xi, int l)
{
    __shared__ __align__(16) unsigned short h1[16][72];
    __shared__ __align__(16) unsigned short h2[16][72];
    const int lane = threadIdx.x & 63;
    const int w = threadIdx.x >> 6;
    const int n0 = blockIdx.x * 16;
    const int r = lane & 15, g = lane >> 4;

    // fc0: K=672, 21 MFMA steps split into 2 independent chains
    const short* Ap = (const short*)cat + (size_t)(n0 + r) * KPAD + g * 8;
    const short* Bp = w0f + ((size_t)l * NKK * 256 + w * 64 + lane) * 8;
    float bv = b0[l * HD + w * 16 + r];
    float4v accA = {bv, bv, bv, bv};
    float4v accB = {0.f, 0.f, 0.f, 0.f};
    #pragma unroll 5
    for (int kk = 0; kk < 20; kk += 2) {
        short8 aA = *(const short8*)(Ap + kk * 32);
        short8 bA = *(const short8*)(Bp + (size_t)kk * 2048);
        accA = __builtin_amdgcn_mfma_f32_16x16x32_bf16(aA, bA, accA, 0, 0, 0);
        short8 aB = *(const short8*)(Ap + (kk + 1) * 32);
        short8 bB = *(const short8*)(Bp + (size_t)(kk + 1) * 2048);
        accB = __builtin_amdgcn_mfma_f32_16x16x32_bf16(aB, bB, accB, 0, 0, 0);
    }
    {
        short8 a = *(const short8*)(Ap + 20 * 32);
        short8 b = *(const short8*)(Bp + (size_t)20 * 2048);
        accA = __builtin_amdgcn_mfma_f32_16x16x32_bf16(a, b, accA, 0, 0, 0);
    }
    #pragma unroll
    for (int i = 0; i < 4; ++i)
        h1[g * 4 + i][w * 16 + r] = f2bf(ssp(accA[i] + accB[i]));
    __syncthreads();

    // fc1
    bv = b1[l * HD + w * 16 + r];
    float4v acc1 = {bv, bv, bv, bv};
    #pragma unroll
    for (int kk = 0; kk < 2; ++kk) {
        short8 a = *(const short8*)((const short*)&h1[r][kk * 32 + g * 8]);
        short8 b = *(const short8*)(w1f + ((size_t)(l * 2 + kk) * 256 + w * 64 + lane) * 8);
        acc1 = __builtin_amdgcn_mfma_f32_16x16x32_bf16(a, b, acc1, 0, 0, 0);
    }
    #pragma unroll
    for (int i = 0; i < 4; ++i)
        h2[g * 4 + i][w * 16 + r] = f2bf(ssp(acc1[i]));
    __syncthreads();

    // fc2 + residual
    bv = b2[l * DIM + w * 16 + r];
    float4v acc2 = {bv, bv, bv, bv};
    #pragma unroll
    for (int kk = 0; kk < 2; ++kk) {
        short8 a = *(const short8*)((const short*)&h2[r][kk * 32 + g * 8]);
        short8 b = *(const short8*)(w2f + ((size_t)(l * 2 + kk) * 256 + w * 64 + lane) * 8);
        acc2 = __builtin_amdgcn_mfma_f32_16x16x32_bf16(a, b, acc2, 0, 0, 0);
    }
    #pragma unroll
    for (int i = 0; i < 4; ++i)
        xi[(size_t)(n0 + g * 4 + i) * DIM + w * 16 + r] += acc2[i];
}

extern "C" void kernel_launch(void* const* d_in, const int* in_sizes, int n_in,
                              void* d_out, int out_size, void* d_ws, size_t ws_size,
                              hipStream_t stream) {
    const int*   species = (const int*)  d_in[0];
    const int*   esrc    = (const int*)  d_in[1];
    const int*   edst    = (const int*)  d_in[2];
    const float* dist    = (const float*)d_in[3];
    const float* sw      = (const float*)d_in[4];
    const float* bo      = (const float*)d_in[5];
    const float* Wsp     = (const float*)d_in[6];
    const float* Wsm     = (const float*)d_in[7];
    const float* bsm     = (const float*)d_in[8];
    const float* w0      = (const float*)d_in[9];
    const float* b0      = (const float*)d_in[10];
    const float* w1      = (const float*)d_in[11];
    const float* b1      = (const float*)d_in[12];
    const float* w2      = (const float*)d_in[13];
    const float* b2      = (const float*)d_in[14];

    float* xi = (float*)d_out;   // N x 64 fp32, updated in place

    // ws layout: u16 E*48 ush | si N*16 f | mi16 N*16 ush | medge E*16 ush |
    //            cat N*672 ush | w0f | w1f | w2f | rowptr
    unsigned short* u16   = (unsigned short*)d_ws;
    float*          si    = (float*)(u16 + (size_t)N_EDGES * 48);
    unsigned short* mi16  = (unsigned short*)(si + (size_t)N_NODES * SUB);
    unsigned short* medge = mi16 + (size_t)N_NODES * SUB;
    unsigned short* cat   = medge + (size_t)N_EDGES * 16;
    short* w0f = (short*)(cat + (size_t)N_NODES * KPAD);
    short* w1f = w0f + (size_t)LAYERS * NKK * 2048;
    short* w2f = w1f + (size_t)LAYERS * 2 * 2048;
    int* rowptr = (int*)(w2f + (size_t)LAYERS * 2 * 2048);

    k_rowptr<<<(N_NODES + 1 + 255) / 256, 256, 0, stream>>>(esrc, rowptr);
    k_u<<<(N_EDGES * 48 + 255) / 256, 256, 0, stream>>>(dist, sw, bo, u16);
    {
        int total = LAYERS * NKK * 2048 + 2 * LAYERS * 2 * 2048;
        k_packw<<<(total + 255) / 256, 256, 0, stream>>>(w0, w1, w2, w0f, w1f, w2f);
    }
    k_init_xi<<<(N_NODES * DIM + 255) / 256, 256, 0, stream>>>(species, Wsp, xi);

    for (int l = 0; l < LAYERS; ++l) {
        k_h<<<(N_NODES * 2 * SUB + 255) / 256, 256, 0, stream>>>(xi, Wsm, bsm, si, mi16, l);
        k_gather<<<(N_EDGES * 4 + 255) / 256, 256, 0, stream>>>(edst, mi16, medge);
        k_agg<<<N_NODES / 2, 256, 0, stream>>>(rowptr, u16, medge, si, cat);
        k_mlp<<<N_NODES / 16, 256, 0, stream>>>(cat, w0f, b0, w1f, b1, w2f, b2, xi, l);
    }
}

// Round 8
// 204.021 us; speedup vs baseline: 1.3401x; 1.0876x over previous
//
#include <hip/hip_runtime.h>
#include <math.h>

#define N_NODES 20000
#define N_EDGES 320000
#define DIM 64
#define SUB 16
#define NRBF 8
#define NB 5
#define LAYERS 3
#define FCIN (NRBF*SUB*NB + SUB)   // 656
#define KPAD 672                   // 21 * 32
#define NKK 21
#define HD 64
#define CUTOFF 5.0f
#define NPB 8                      // nodes per k_agg block
#define CHUNK 128                  // edges staged per chunk

typedef __attribute__((ext_vector_type(8))) short short8;
typedef __attribute__((ext_vector_type(4))) float float4v;
typedef __attribute__((ext_vector_type(4))) unsigned short ushort4v;

__device__ __forceinline__ float ssp(float x) {
    float sp = fmaxf(x, 0.0f) + log1pf(expf(-fabsf(x)));
    return sp - 0.69314718055994530942f;
}

__device__ __forceinline__ unsigned short f2bf(float x) {
    unsigned int u = __float_as_uint(x);
    unsigned int r = (u + 0x7FFFu + ((u >> 16) & 1u)) >> 16;
    return (unsigned short)r;
}
__device__ __forceinline__ float bf2f(unsigned short s) {
    unsigned int u = ((unsigned int)s) << 16;
    return __uint_as_float(u);
}

// --- one-time kernels -------------------------------------------------------

__global__ void k_rowptr(const int* __restrict__ esrc, int* __restrict__ rowptr) {
    int n = blockIdx.x * blockDim.x + threadIdx.x;
    if (n > N_NODES) return;
    int a = 0, b = N_EDGES;
    while (a < b) { int m = (a + b) >> 1; if (esrc[m] < n) a = m + 1; else b = m; }
    rowptr[n] = a;
}

// u16[e][g*12+j] = bf16( sw[e] * rb[r] * bo[b] ), p=g+4j, r=p/5, b=p%5; j=10,11 pad=0
__global__ void k_u(const float* __restrict__ dist, const float* __restrict__ sw,
                    const float* __restrict__ bo, unsigned short* __restrict__ u16) {
    int i = blockIdx.x * blockDim.x + threadIdx.x;
    if (i >= N_EDGES * 48) return;
    int e = i / 48, t = i - e * 48;
    int g = t / 12, j = t - g * 12;
    float v = 0.0f;
    if (j < 10) {
        int p = g + 4 * j;
        int r = p / 5, b = p - r * 5;
        float mu = (CUTOFF / (NRBF - 1)) * (float)r;
        float inv_sigma = (float)NRBF / CUTOFF;
        float z = (dist[e] - mu) * inv_sigma;
        v = sw[e] * expf(-0.5f * z * z) * bo[e * NB + b];
    }
    u16[i] = f2bf(v);
}

// Pack weights into MFMA B-fragment order (bf16). Same layout as round 3.
__global__ void k_packw(const float* __restrict__ w0, const float* __restrict__ w1,
                        const float* __restrict__ w2,
                        short* __restrict__ w0f, short* __restrict__ w1f,
                        short* __restrict__ w2f) {
    int i = blockIdx.x * blockDim.x + threadIdx.x;
    const int SZ0 = LAYERS * NKK * 4 * 64 * 8;       // 129024
    const int SZ12 = LAYERS * 2 * 4 * 64 * 8;        // 12288
    if (i < SZ0) {
        int j = i & 7, t = i >> 3;
        int lane = t & 63; t >>= 6;
        int nf = t & 3; t >>= 2;
        int kk = t % NKK, l = t / NKK;
        int kp = kk * 32 + (lane >> 4) * 8 + j;
        int col = nf * 16 + (lane & 15);
        float v = 0.0f;
        if (kp < FCIN) {
            int orig;
            if (kp < 640) {
                int j10 = kp >> 6, rem = kp & 63, g = rem >> 4, s = rem & 15;
                int p = g + 4 * j10;
                orig = (p / 5) * 80 + s * 5 + (p - 5 * (p / 5));
            } else orig = kp;
            v = w0[((size_t)l * FCIN + orig) * HD + col];
        }
        w0f[i] = (short)f2bf(v);
        return;
    }
    i -= SZ0;
    if (i < 2 * SZ12) {
        const float* W = (i < SZ12) ? w1 : w2;
        short* Wf = (i < SZ12) ? w1f : w2f;
        int ii = (i < SZ12) ? i : i - SZ12;
        int j = ii & 7, t = ii >> 3;
        int lane = t & 63; t >>= 6;
        int nf = t & 3; t >>= 2;
        int kk = t & 1, l = t >> 1;
        int kp = kk * 32 + (lane >> 4) * 8 + j;
        int col = nf * 16 + (lane & 15);
        Wf[ii] = (short)f2bf(W[((size_t)l * HD + kp) * HD + col]);
    }
}

__global__ void k_init_xi(const int* __restrict__ species,
                          const float* __restrict__ Wsp,
                          float* __restrict__ xi) {
    int i = blockIdx.x * blockDim.x + threadIdx.x;
    if (i >= N_NODES * DIM) return;
    int n = i >> 6, d = i & 63;
    xi[i] = Wsp[species[n] * DIM + d];
}

// --- per-layer kernels ------------------------------------------------------

// h = xi @ W_sm[l] + b_sm[l]; si fp32, mi bf16
__global__ void k_h(const float* __restrict__ xi,
                    const float* __restrict__ Wsm, const float* __restrict__ bsm,
                    float* __restrict__ si, unsigned short* __restrict__ mi16, int l) {
    int i = blockIdx.x * blockDim.x + threadIdx.x;
    if (i >= N_NODES * 2 * SUB) return;
    int n = i >> 5, j = i & 31;
    const float* W = Wsm + l * DIM * 2 * SUB;
    const float* xr = xi + n * DIM;
    float v = bsm[l * 2 * SUB + j];
    #pragma unroll
    for (int d = 0; d < DIM; ++d) v = fmaf(xr[d], W[d * 2 * SUB + j], v);
    if (j < SUB) si[n * SUB + j] = v;
    else         mi16[n * SUB + (j - SUB)] = f2bf(v);
}

// Per-edge consume body from LDS (el = e - chunk base); acc array A[10].
#define AGG_BODY_LDS(el, A)                                                   \
    {                                                                         \
        const unsigned short* up = u_s + (el) * 48 + g * 12;                  \
        ushort4v ua = *(const ushort4v*)(up);                                 \
        ushort4v ub = *(const ushort4v*)(up + 4);                             \
        unsigned int uc = *(const unsigned int*)(up + 8);                     \
        float m = bf2f(m_s[(el) * 16 + s]);                                   \
        A[0] = fmaf(bf2f(ua.x), m, A[0]); A[1] = fmaf(bf2f(ua.y), m, A[1]);   \
        A[2] = fmaf(bf2f(ua.z), m, A[2]); A[3] = fmaf(bf2f(ua.w), m, A[3]);   \
        A[4] = fmaf(bf2f(ub.x), m, A[4]); A[5] = fmaf(bf2f(ub.y), m, A[5]);   \
        A[6] = fmaf(bf2f(ub.z), m, A[6]); A[7] = fmaf(bf2f(ub.w), m, A[7]);   \
        A[8] = fmaf(bf2f((unsigned short)(uc & 0xFFFFu)), m, A[8]);           \
        A[9] = fmaf(bf2f((unsigned short)(uc >> 16)), m, A[9]);               \
    }

// Aggregation with LDS staging. Block = 256 threads = 4 waves = 8 nodes
// (wave w owns nodes 2w, 2w+1). The block's edge window [rowptr[n0],
// rowptr[n0+8]) is contiguous; staged in 128-edge chunks: u16 coalesced,
// mi rows gathered via edst during staging (no medge buffer needed).
__global__ __launch_bounds__(256) void k_agg(
    const int* __restrict__ rowptr, const int* __restrict__ edst,
    const unsigned short* __restrict__ u16,
    const unsigned short* __restrict__ mi16,
    const float* __restrict__ si,
    unsigned short* __restrict__ cat)
{
    __shared__ __align__(16) unsigned short u_s[CHUNK * 48];  // 12 KB
    __shared__ __align__(16) unsigned short m_s[CHUNK * 16];  // 4 KB
    const int tid = threadIdx.x;
    const int lane = tid & 63;
    const int w = tid >> 6;
    const int n0 = blockIdx.x * NPB;
    const int s = lane & 15;
    const int g = lane >> 4;

    const int nA = n0 + 2 * w;
    const int loA = rowptr[nA], hiA = rowptr[nA + 1], hiB = rowptr[nA + 2];
    const int blk_lo = rowptr[n0], blk_hi = rowptr[n0 + NPB];

    float a[10], c[10];
    #pragma unroll
    for (int j = 0; j < 10; ++j) { a[j] = 0.0f; c[j] = 0.0f; }

    for (int ck = blk_lo; ck < blk_hi; ck += CHUNK) {
        const int len = min(CHUNK, blk_hi - ck);
        __syncthreads();
        // stage u16: len*6 x 16B, fully coalesced
        for (int i = tid; i < len * 6; i += 256)
            *(uint4*)&u_s[i * 8] = *(const uint4*)(u16 + (size_t)ck * 48 + i * 8);
        // stage m: len*2 x 16B gathers from L2-resident mi16
        for (int i = tid; i < len * 2; i += 256) {
            int e = ck + (i >> 1);
            int h = i & 1;
            int dst = edst[e];
            *(uint4*)&m_s[i * 8] = *(const uint4*)(mi16 + dst * 16 + h * 8);
        }
        __syncthreads();
        // consume: node A then node B, each the intersection with this chunk
        {
            int beg = max(loA, ck), end = min(hiA, ck + len);
            for (int e = beg; e < end; ++e) AGG_BODY_LDS(e - ck, a)
        }
        {
            int beg = max(hiA, ck), end = min(hiB, ck + len);
            for (int e = beg; e < end; ++e) AGG_BODY_LDS(e - ck, c)
        }
    }

    unsigned short* cp = cat + (size_t)nA * KPAD;
    #pragma unroll
    for (int j = 0; j < 10; ++j) cp[j * 64 + lane] = f2bf(a[j]);
    if (lane < SUB)      cp[640 + lane] = f2bf(si[(size_t)nA * SUB + lane]);
    else if (lane < 32)  cp[640 + lane] = 0;
    cp += KPAD;
    #pragma unroll
    for (int j = 0; j < 10; ++j) cp[j * 64 + lane] = f2bf(c[j]);
    if (lane < SUB)      cp[640 + lane] = f2bf(si[(size_t)(nA + 1) * SUB + lane]);
    else if (lane < 32)  cp[640 + lane] = 0;
}

// Fused MFMA MLP: 16 nodes/block, 4 waves; wave w owns output cols [16w,16w+16),
// full K. fc0 uses two independent MFMA accumulator chains for ILP.
__global__ __launch_bounds__(256) void k_mlp(
    const unsigned short* __restrict__ cat,
    const short* __restrict__ w0f, const float* __restrict__ b0,
    const short* __restrict__ w1f, const float* __restrict__ b1,
    const short* __restrict__ w2f, const float* __restrict__ b2,
    float* __restrict__ xi, int l)
{
    __shared__ __align__(16) unsigned short h1[16][72];
    __shared__ __align__(16) unsigned short h2[16][72];
    const int lane = threadIdx.x & 63;
    const int w = threadIdx.x >> 6;
    const int n0 = blockIdx.x * 16;
    const int r = lane & 15, g = lane >> 4;

    // fc0: K=672, 21 MFMA steps split into 2 independent chains
    const short* Ap = (const short*)cat + (size_t)(n0 + r) * KPAD + g * 8;
    const short* Bp = w0f + ((size_t)l * NKK * 256 + w * 64 + lane) * 8;
    float bv = b0[l * HD + w * 16 + r];
    float4v accA = {bv, bv, bv, bv};
    float4v accB = {0.f, 0.f, 0.f, 0.f};
    #pragma unroll 5
    for (int kk = 0; kk < 20; kk += 2) {
        short8 aA = *(const short8*)(Ap + kk * 32);
        short8 bA = *(const short8*)(Bp + (size_t)kk * 2048);
        accA = __builtin_amdgcn_mfma_f32_16x16x32_bf16(aA, bA, accA, 0, 0, 0);
        short8 aB = *(const short8*)(Ap + (kk + 1) * 32);
        short8 bB = *(const short8*)(Bp + (size_t)(kk + 1) * 2048);
        accB = __builtin_amdgcn_mfma_f32_16x16x32_bf16(aB, bB, accB, 0, 0, 0);
    }
    {
        short8 a = *(const short8*)(Ap + 20 * 32);
        short8 b = *(const short8*)(Bp + (size_t)20 * 2048);
        accA = __builtin_amdgcn_mfma_f32_16x16x32_bf16(a, b, accA, 0, 0, 0);
    }
    #pragma unroll
    for (int i = 0; i < 4; ++i)
        h1[g * 4 + i][w * 16 + r] = f2bf(ssp(accA[i] + accB[i]));
    __syncthreads();

    // fc1
    bv = b1[l * HD + w * 16 + r];
    float4v acc1 = {bv, bv, bv, bv};
    #pragma unroll
    for (int kk = 0; kk < 2; ++kk) {
        short8 a = *(const short8*)((const short*)&h1[r][kk * 32 + g * 8]);
        short8 b = *(const short8*)(w1f + ((size_t)(l * 2 + kk) * 256 + w * 64 + lane) * 8);
        acc1 = __builtin_amdgcn_mfma_f32_16x16x32_bf16(a, b, acc1, 0, 0, 0);
    }
    #pragma unroll
    for (int i = 0; i < 4; ++i)
        h2[g * 4 + i][w * 16 + r] = f2bf(ssp(acc1[i]));
    __syncthreads();

    // fc2 + residual
    bv = b2[l * DIM + w * 16 + r];
    float4v acc2 = {bv, bv, bv, bv};
    #pragma unroll
    for (int kk = 0; kk < 2; ++kk) {
        short8 a = *(const short8*)((const short*)&h2[r][kk * 32 + g * 8]);
        short8 b = *(const short8*)(w2f + ((size_t)(l * 2 + kk) * 256 + w * 64 + lane) * 8);
        acc2 = __builtin_amdgcn_mfma_f32_16x16x32_bf16(a, b, acc2, 0, 0, 0);
    }
    #pragma unroll
    for (int i = 0; i < 4; ++i)
        xi[(size_t)(n0 + g * 4 + i) * DIM + w * 16 + r] += acc2[i];
}

extern "C" void kernel_launch(void* const* d_in, const int* in_sizes, int n_in,
                              void* d_out, int out_size, void* d_ws, size_t ws_size,
                              hipStream_t stream) {
    const int*   species = (const int*)  d_in[0];
    const int*   esrc    = (const int*)  d_in[1];
    const int*   edst    = (const int*)  d_in[2];
    const float* dist    = (const float*)d_in[3];
    const float* sw      = (const float*)d_in[4];
    const float* bo      = (const float*)d_in[5];
    const float* Wsp     = (const float*)d_in[6];
    const float* Wsm     = (const float*)d_in[7];
    const float* bsm     = (const float*)d_in[8];
    const float* w0      = (const float*)d_in[9];
    const float* b0      = (const float*)d_in[10];
    const float* w1      = (const float*)d_in[11];
    const float* b1      = (const float*)d_in[12];
    const float* w2      = (const float*)d_in[13];
    const float* b2      = (const float*)d_in[14];

    float* xi = (float*)d_out;   // N x 64 fp32, updated in place

    // ws layout: u16 E*48 ush | si N*16 f | mi16 N*16 ush | cat N*672 ush |
    //            w0f | w1f | w2f | rowptr
    unsigned short* u16   = (unsigned short*)d_ws;
    float*          si    = (float*)(u16 + (size_t)N_EDGES * 48);
    unsigned short* mi16  = (unsigned short*)(si + (size_t)N_NODES * SUB);
    unsigned short* cat   = mi16 + (size_t)N_NODES * SUB;
    short* w0f = (short*)(cat + (size_t)N_NODES * KPAD);
    short* w1f = w0f + (size_t)LAYERS * NKK * 2048;
    short* w2f = w1f + (size_t)LAYERS * 2 * 2048;
    int* rowptr = (int*)(w2f + (size_t)LAYERS * 2 * 2048);

    k_rowptr<<<(N_NODES + 1 + 255) / 256, 256, 0, stream>>>(esrc, rowptr);
    k_u<<<(N_EDGES * 48 + 255) / 256, 256, 0, stream>>>(dist, sw, bo, u16);
    {
        int total = LAYERS * NKK * 2048 + 2 * LAYERS * 2 * 2048;
        k_packw<<<(total + 255) / 256, 256, 0, stream>>>(w0, w1, w2, w0f, w1f, w2f);
    }
    k_init_xi<<<(N_NODES * DIM + 255) / 256, 256, 0, stream>>>(species, Wsp, xi);

    for (int l = 0; l < LAYERS; ++l) {
        k_h<<<(N_NODES * 2 * SUB + 255) / 256, 256, 0, stream>>>(xi, Wsm, bsm, si, mi16, l);
        k_agg<<<N_NODES / NPB, 256, 0, stream>>>(rowptr, edst, u16, mi16, si, cat);
        k_mlp<<<N_NODES / 16, 256, 0, stream>>>(cat, w0f, b0, w1f, b1, w2f, b2, xi, l);
    }
}

// Round 9
// 186.835 us; speedup vs baseline: 1.4634x; 1.0920x over previous
//
#include <hip/hip_runtime.h>
#include <math.h>

#define N_NODES 20000
#define N_EDGES 320000
#define E_PAD 320032               // N_EDGES + 32, multiple of 8
#define DIM 64
#define SUB 16
#define NRBF 8
#define NB 5
#define LAYERS 3
#define FCIN (NRBF*SUB*NB + SUB)   // 656
#define KPAD 672                   // 21 * 32
#define NKK 21
#define HD 64
#define CUTOFF 5.0f

typedef __attribute__((ext_vector_type(8))) short short8;
typedef __attribute__((ext_vector_type(4))) float float4v;

__device__ __forceinline__ float ssp(float x) {
    float sp = fmaxf(x, 0.0f) + log1pf(expf(-fabsf(x)));
    return sp - 0.69314718055994530942f;
}

__device__ __forceinline__ unsigned short f2bf(float x) {
    unsigned int u = __float_as_uint(x);
    unsigned int r = (u + 0x7FFFu + ((u >> 16) & 1u)) >> 16;
    return (unsigned short)r;
}
__device__ __forceinline__ float bf2f(unsigned short s) {
    unsigned int u = ((unsigned int)s) << 16;
    return __uint_as_float(u);
}

// --- one-time kernels -------------------------------------------------------

__global__ void k_rowptr(const int* __restrict__ esrc, int* __restrict__ rowptr) {
    int n = blockIdx.x * blockDim.x + threadIdx.x;
    if (n > N_NODES) return;
    int a = 0, b = N_EDGES;
    while (a < b) { int m = (a + b) >> 1; if (esrc[m] < n) a = m + 1; else b = m; }
    rowptr[n] = a;
}

// uT[p][e] = bf16( sw[e] * rb[p/5] * bo[e][p%5] ) for p<40; rows 40..47 zero.
// p-major (transposed) so k_agg A-fragments are 16B contiguous loads.
__global__ void k_u(const float* __restrict__ dist, const float* __restrict__ sw,
                    const float* __restrict__ bo, unsigned short* __restrict__ uT) {
    int e = blockIdx.x * blockDim.x + threadIdx.x;
    if (e >= E_PAD) return;
    bool oke = e < N_EDGES;
    float d  = oke ? dist[e] : 0.0f;
    float s  = oke ? sw[e]   : 0.0f;
    float rbv[NRBF], bov[NB];
    #pragma unroll
    for (int r = 0; r < NRBF; ++r) {
        float mu = (CUTOFF / (NRBF - 1)) * (float)r;
        float z = (d - mu) * ((float)NRBF / CUTOFF);
        rbv[r] = s * expf(-0.5f * z * z);
    }
    #pragma unroll
    for (int b = 0; b < NB; ++b) bov[b] = oke ? bo[e * NB + b] : 0.0f;
    #pragma unroll
    for (int p = 0; p < 48; ++p) {
        float v = (p < 40) ? rbv[p / 5] * bov[p % 5] : 0.0f;
        uT[(size_t)p * E_PAD + e] = f2bf(v);
    }
}

// Pack weights into MFMA B-fragment order (bf16). Same layout as round 3.
__global__ void k_packw(const float* __restrict__ w0, const float* __restrict__ w1,
                        const float* __restrict__ w2,
                        short* __restrict__ w0f, short* __restrict__ w1f,
                        short* __restrict__ w2f) {
    int i = blockIdx.x * blockDim.x + threadIdx.x;
    const int SZ0 = LAYERS * NKK * 4 * 64 * 8;       // 129024
    const int SZ12 = LAYERS * 2 * 4 * 64 * 8;        // 12288
    if (i < SZ0) {
        int j = i & 7, t = i >> 3;
        int lane = t & 63; t >>= 6;
        int nf = t & 3; t >>= 2;
        int kk = t % NKK, l = t / NKK;
        int kp = kk * 32 + (lane >> 4) * 8 + j;
        int col = nf * 16 + (lane & 15);
        float v = 0.0f;
        if (kp < FCIN) {
            int orig;
            if (kp < 640) {
                int j10 = kp >> 6, rem = kp & 63, g = rem >> 4, s = rem & 15;
                int p = g + 4 * j10;
                orig = (p / 5) * 80 + s * 5 + (p - 5 * (p / 5));
            } else orig = kp;
            v = w0[((size_t)l * FCIN + orig) * HD + col];
        }
        w0f[i] = (short)f2bf(v);
        return;
    }
    i -= SZ0;
    if (i < 2 * SZ12) {
        const float* W = (i < SZ12) ? w1 : w2;
        short* Wf = (i < SZ12) ? w1f : w2f;
        int ii = (i < SZ12) ? i : i - SZ12;
        int j = ii & 7, t = ii >> 3;
        int lane = t & 63; t >>= 6;
        int nf = t & 3; t >>= 2;
        int kk = t & 1, l = t >> 1;
        int kp = kk * 32 + (lane >> 4) * 8 + j;
        int col = nf * 16 + (lane & 15);
        Wf[ii] = (short)f2bf(W[((size_t)l * HD + kp) * HD + col]);
    }
}

__global__ void k_init_xi(const int* __restrict__ species,
                          const float* __restrict__ Wsp,
                          float* __restrict__ xi) {
    int i = blockIdx.x * blockDim.x + threadIdx.x;
    if (i >= N_NODES * DIM) return;
    int n = i >> 6, d = i & 63;
    xi[i] = Wsp[species[n] * DIM + d];
}

// --- per-layer kernels ------------------------------------------------------

// h = xi @ W_sm[l] + b_sm[l]; si fp32, mi bf16
__global__ void k_h(const float* __restrict__ xi,
                    const float* __restrict__ Wsm, const float* __restrict__ bsm,
                    float* __restrict__ si, unsigned short* __restrict__ mi16, int l) {
    int i = blockIdx.x * blockDim.x + threadIdx.x;
    if (i >= N_NODES * 2 * SUB) return;
    int n = i >> 5, j = i & 31;
    const float* W = Wsm + l * DIM * 2 * SUB;
    const float* xr = xi + n * DIM;
    float v = bsm[l * 2 * SUB + j];
    #pragma unroll
    for (int d = 0; d < DIM; ++d) v = fmaf(xr[d], W[d * 2 * SUB + j], v);
    if (j < SUB) si[n * SUB + j] = v;
    else         mi16[n * SUB + (j - SUB)] = f2bf(v);
}

// MFMA aggregation. Per node: C[p][s] = sum_e u[e][p] * mi[dst_e][s]
// = 3 p-tiles (16x16) x ceil-aligned K-chunks of 32 edges.
// A (uT) from global, 16B contiguous per fragment (chunks 32-aligned).
// B (mi rows) gathered per-chunk into per-wave LDS; out-of-node k's zeroed.
// Block = 4 waves = 8 nodes (wave w -> nodes 2w, 2w+1). No barriers.
__global__ __launch_bounds__(256) void k_agg(
    const int* __restrict__ rowptr, const int* __restrict__ edst,
    const unsigned short* __restrict__ uT,
    const unsigned short* __restrict__ mi16,
    const float* __restrict__ si,
    unsigned short* __restrict__ cat)
{
    __shared__ unsigned short m_s[4][32][16];   // 4 KB, one [32][16] per wave
    const int lane = threadIdx.x & 63;
    const int w = threadIdx.x >> 6;
    const int x = lane & 15, g = lane >> 4;
    const int er = lane >> 1, half = lane & 1;

    for (int nn = 0; nn < 2; ++nn) {
        const int n = blockIdx.x * 8 + 2 * w + nn;
        const int lo = rowptr[n], hi = rowptr[n + 1];
        float4v acc0 = {0.f,0.f,0.f,0.f};
        float4v acc1 = {0.f,0.f,0.f,0.f};
        float4v acc2 = {0.f,0.f,0.f,0.f};

        for (int ba = lo & ~31; ba < hi; ba += 32) {
            // drain prior ds_reads before overwriting m_s (wave-synchronous reuse)
            asm volatile("s_waitcnt lgkmcnt(0)" ::: "memory");
            // stage: 2 lanes per edge row, 16B each
            {
                int e = min(ba + er, N_EDGES - 1);
                int dst = edst[e];
                uint4 v = *(const uint4*)(mi16 + (size_t)dst * 16 + half * 8);
                *(uint4*)&m_s[w][er][half * 8] = v;
            }
            asm volatile("s_waitcnt lgkmcnt(0)" ::: "memory");

            // B fragment: B[k=g*8+j][s=x], zero outside [lo,hi)
            const int klo = lo - ba;       // >0 only in first chunk
            const int khi = hi - ba;       // <32 only in last chunk
            short8 bq;
            if (klo <= 0 && khi >= 32) {
                #pragma unroll
                for (int j = 0; j < 8; ++j) bq[j] = (short)m_s[w][g * 8 + j][x];
            } else {
                #pragma unroll
                for (int j = 0; j < 8; ++j) {
                    int k = g * 8 + j;
                    bq[j] = (k >= klo && k < khi) ? (short)m_s[w][k][x] : (short)0;
                }
            }

            // A fragments: A[m=x][k=g*8+j] = uT[t*16+x][ba+k]; 16B aligned
            const unsigned short* ap = uT + (size_t)x * E_PAD + ba + g * 8;
            short8 a0 = *(const short8*)(ap);
            short8 a1 = *(const short8*)(ap + (size_t)16 * E_PAD);
            short8 a2 = *(const short8*)(ap + (size_t)32 * E_PAD);
            acc0 = __builtin_amdgcn_mfma_f32_16x16x32_bf16(a0, bq, acc0, 0, 0, 0);
            acc1 = __builtin_amdgcn_mfma_f32_16x16x32_bf16(a1, bq, acc1, 0, 0, 0);
            acc2 = __builtin_amdgcn_mfma_f32_16x16x32_bf16(a2, bq, acc2, 0, 0, 0);
        }

        // C: row p = t*16 + g*4 + i, col s = x -> cat'[kp], kp=(p>>2)*64+(p&3)*16+x
        unsigned short* cp = cat + (size_t)n * KPAD;
        #pragma unroll
        for (int i = 0; i < 4; ++i) {
            int p = g * 4 + i;
            cp[(p >> 2) * 64 + (p & 3) * 16 + x] = f2bf(acc0[i]);
        }
        #pragma unroll
        for (int i = 0; i < 4; ++i) {
            int p = 16 + g * 4 + i;
            cp[(p >> 2) * 64 + (p & 3) * 16 + x] = f2bf(acc1[i]);
        }
        if (g < 2) {
            #pragma unroll
            for (int i = 0; i < 4; ++i) {
                int p = 32 + g * 4 + i;
                cp[(p >> 2) * 64 + (p & 3) * 16 + x] = f2bf(acc2[i]);
            }
        }
        if (lane < SUB)      cp[640 + lane] = f2bf(si[(size_t)n * SUB + lane]);
        else if (lane < 32)  cp[640 + lane] = 0;   // pad cols 656..671
    }
}

// Fused MFMA MLP: 16 nodes/block, 4 waves; wave w owns output cols [16w,16w+16),
// full K. fc0 uses two independent MFMA accumulator chains for ILP.
__global__ __launch_bounds__(256) void k_mlp(
    const unsigned short* __restrict__ cat,
    const short* __restrict__ w0f, const float* __restrict__ b0,
    const short* __restrict__ w1f, const float* __restrict__ b1,
    const short* __restrict__ w2f, const float* __restrict__ b2,
    float* __restrict__ xi, int l)
{
    __shared__ __align__(16) unsigned short h1[16][72];
    __shared__ __align__(16) unsigned short h2[16][72];
    const int lane = threadIdx.x & 63;
    const int w = threadIdx.x >> 6;
    const int n0 = blockIdx.x * 16;
    const int r = lane & 15, g = lane >> 4;

    // fc0: K=672, 21 MFMA steps split into 2 independent chains
    const short* Ap = (const short*)cat + (size_t)(n0 + r) * KPAD + g * 8;
    const short* Bp = w0f + ((size_t)l * NKK * 256 + w * 64 + lane) * 8;
    float bv = b0[l * HD + w * 16 + r];
    float4v accA = {bv, bv, bv, bv};
    float4v accB = {0.f, 0.f, 0.f, 0.f};
    #pragma unroll 5
    for (int kk = 0; kk < 20; kk += 2) {
        short8 aA = *(const short8*)(Ap + kk * 32);
        short8 bA = *(const short8*)(Bp + (size_t)kk * 2048);
        accA = __builtin_amdgcn_mfma_f32_16x16x32_bf16(aA, bA, accA, 0, 0, 0);
        short8 aB = *(const short8*)(Ap + (kk + 1) * 32);
        short8 bB = *(const short8*)(Bp + (size_t)(kk + 1) * 2048);
        accB = __builtin_amdgcn_mfma_f32_16x16x32_bf16(aB, bB, accB, 0, 0, 0);
    }
    {
        short8 a = *(const short8*)(Ap + 20 * 32);
        short8 b = *(const short8*)(Bp + (size_t)20 * 2048);
        accA = __builtin_amdgcn_mfma_f32_16x16x32_bf16(a, b, accA, 0, 0, 0);
    }
    #pragma unroll
    for (int i = 0; i < 4; ++i)
        h1[g * 4 + i][w * 16 + r] = f2bf(ssp(accA[i] + accB[i]));
    __syncthreads();

    // fc1
    bv = b1[l * HD + w * 16 + r];
    float4v acc1 = {bv, bv, bv, bv};
    #pragma unroll
    for (int kk = 0; kk < 2; ++kk) {
        short8 a = *(const short8*)((const short*)&h1[r][kk * 32 + g * 8]);
        short8 b = *(const short8*)(w1f + ((size_t)(l * 2 + kk) * 256 + w * 64 + lane) * 8);
        acc1 = __builtin_amdgcn_mfma_f32_16x16x32_bf16(a, b, acc1, 0, 0, 0);
    }
    #pragma unroll
    for (int i = 0; i < 4; ++i)
        h2[g * 4 + i][w * 16 + r] = f2bf(ssp(acc1[i]));
    __syncthreads();

    // fc2 + residual
    bv = b2[l * DIM + w * 16 + r];
    float4v acc2 = {bv, bv, bv, bv};
    #pragma unroll
    for (int kk = 0; kk < 2; ++kk) {
        short8 a = *(const short8*)((const short*)&h2[r][kk * 32 + g * 8]);
        short8 b = *(const short8*)(w2f + ((size_t)(l * 2 + kk) * 256 + w * 64 + lane) * 8);
        acc2 = __builtin_amdgcn_mfma_f32_16x16x32_bf16(a, b, acc2, 0, 0, 0);
    }
    #pragma unroll
    for (int i = 0; i < 4; ++i)
        xi[(size_t)(n0 + g * 4 + i) * DIM + w * 16 + r] += acc2[i];
}

extern "C" void kernel_launch(void* const* d_in, const int* in_sizes, int n_in,
                              void* d_out, int out_size, void* d_ws, size_t ws_size,
                              hipStream_t stream) {
    const int*   species = (const int*)  d_in[0];
    const int*   esrc    = (const int*)  d_in[1];
    const int*   edst    = (const int*)  d_in[2];
    const float* dist    = (const float*)d_in[3];
    const float* sw      = (const float*)d_in[4];
    const float* bo      = (const float*)d_in[5];
    const float* Wsp     = (const float*)d_in[6];
    const float* Wsm     = (const float*)d_in[7];
    const float* bsm     = (const float*)d_in[8];
    const float* w0      = (const float*)d_in[9];
    const float* b0      = (const float*)d_in[10];
    const float* w1      = (const float*)d_in[11];
    const float* b1      = (const float*)d_in[12];
    const float* w2      = (const float*)d_in[13];
    const float* b2      = (const float*)d_in[14];

    float* xi = (float*)d_out;   // N x 64 fp32, updated in place

    // ws layout: uT 48*E_PAD ush | si N*16 f | mi16 N*16 ush | cat N*672 ush |
    //            w0f | w1f | w2f | rowptr
    unsigned short* uT    = (unsigned short*)d_ws;
    float*          si    = (float*)(uT + (size_t)48 * E_PAD);
    unsigned short* mi16  = (unsigned short*)(si + (size_t)N_NODES * SUB);
    unsigned short* cat   = mi16 + (size_t)N_NODES * SUB;
    short* w0f = (short*)(cat + (size_t)N_NODES * KPAD);
    short* w1f = w0f + (size_t)LAYERS * NKK * 2048;
    short* w2f = w1f + (size_t)LAYERS * 2 * 2048;
    int* rowptr = (int*)(w2f + (size_t)LAYERS * 2 * 2048);

    k_rowptr<<<(N_NODES + 1 + 255) / 256, 256, 0, stream>>>(esrc, rowptr);
    k_u<<<(E_PAD + 255) / 256, 256, 0, stream>>>(dist, sw, bo, uT);
    {
        int total = LAYERS * NKK * 2048 + 2 * LAYERS * 2 * 2048;
        k_packw<<<(total + 255) / 256, 256, 0, stream>>>(w0, w1, w2, w0f, w1f, w2f);
    }
    k_init_xi<<<(N_NODES * DIM + 255) / 256, 256, 0, stream>>>(species, Wsp, xi);

    for (int l = 0; l < LAYERS; ++l) {
        k_h<<<(N_NODES * 2 * SUB + 255) / 256, 256, 0, stream>>>(xi, Wsm, bsm, si, mi16, l);
        k_agg<<<N_NODES / 8, 256, 0, stream>>>(rowptr, edst, uT, mi16, si, cat);
        k_mlp<<<N_NODES / 16, 256, 0, stream>>>(cat, w0f, b0, w1f, b1, w2f, b2, xi, l);
    }
}

// Round 10
// 168.259 us; speedup vs baseline: 1.6250x; 1.1104x over previous
//
#include <hip/hip_runtime.h>
#include <math.h>

#define N_NODES 20000
#define N_EDGES 320000
#define E_PAD 320032               // N_EDGES + 32, multiple of 8
#define DIM 64
#define SUB 16
#define NRBF 8
#define NB 5
#define LAYERS 3
#define FCIN (NRBF*SUB*NB + SUB)   // 656
#define KPAD 672                   // 21 * 32
#define NKK 21
#define HD 64
#define CUTOFF 5.0f

typedef __attribute__((ext_vector_type(8))) short short8;
typedef __attribute__((ext_vector_type(4))) float float4v;

__device__ __forceinline__ float ssp(float x) {
    float sp = fmaxf(x, 0.0f) + log1pf(expf(-fabsf(x)));
    return sp - 0.69314718055994530942f;
}

__device__ __forceinline__ unsigned short f2bf(float x) {
    unsigned int u = __float_as_uint(x);
    unsigned int r = (u + 0x7FFFu + ((u >> 16) & 1u)) >> 16;
    return (unsigned short)r;
}
__device__ __forceinline__ float bf2f(unsigned short s) {
    unsigned int u = ((unsigned int)s) << 16;
    return __uint_as_float(u);
}

// --- one-time kernels -------------------------------------------------------

__global__ void k_rowptr(const int* __restrict__ esrc, int* __restrict__ rowptr) {
    int n = blockIdx.x * blockDim.x + threadIdx.x;
    if (n > N_NODES) return;
    int a = 0, b = N_EDGES;
    while (a < b) { int m = (a + b) >> 1; if (esrc[m] < n) a = m + 1; else b = m; }
    rowptr[n] = a;
}

// uT[p][e] = bf16( sw[e] * rb[p/5] * bo[e][p%5] ) for p<40; rows 40..47 zero.
__global__ void k_u(const float* __restrict__ dist, const float* __restrict__ sw,
                    const float* __restrict__ bo, unsigned short* __restrict__ uT) {
    int e = blockIdx.x * blockDim.x + threadIdx.x;
    if (e >= E_PAD) return;
    bool oke = e < N_EDGES;
    float d  = oke ? dist[e] : 0.0f;
    float s  = oke ? sw[e]   : 0.0f;
    float rbv[NRBF], bov[NB];
    #pragma unroll
    for (int r = 0; r < NRBF; ++r) {
        float mu = (CUTOFF / (NRBF - 1)) * (float)r;
        float z = (d - mu) * ((float)NRBF / CUTOFF);
        rbv[r] = s * expf(-0.5f * z * z);
    }
    #pragma unroll
    for (int b = 0; b < NB; ++b) bov[b] = oke ? bo[e * NB + b] : 0.0f;
    #pragma unroll
    for (int p = 0; p < 48; ++p) {
        float v = (p < 40) ? rbv[p / 5] * bov[p % 5] : 0.0f;
        uT[(size_t)p * E_PAD + e] = f2bf(v);
    }
}

// Pack weights into MFMA B-fragment order (bf16). Same layout as round 3.
__global__ void k_packw(const float* __restrict__ w0, const float* __restrict__ w1,
                        const float* __restrict__ w2,
                        short* __restrict__ w0f, short* __restrict__ w1f,
                        short* __restrict__ w2f) {
    int i = blockIdx.x * blockDim.x + threadIdx.x;
    const int SZ0 = LAYERS * NKK * 4 * 64 * 8;       // 129024
    const int SZ12 = LAYERS * 2 * 4 * 64 * 8;        // 12288
    if (i < SZ0) {
        int j = i & 7, t = i >> 3;
        int lane = t & 63; t >>= 6;
        int nf = t & 3; t >>= 2;
        int kk = t % NKK, l = t / NKK;
        int kp = kk * 32 + (lane >> 4) * 8 + j;
        int col = nf * 16 + (lane & 15);
        float v = 0.0f;
        if (kp < FCIN) {
            int orig;
            if (kp < 640) {
                int j10 = kp >> 6, rem = kp & 63, g = rem >> 4, s = rem & 15;
                int p = g + 4 * j10;
                orig = (p / 5) * 80 + s * 5 + (p - 5 * (p / 5));
            } else orig = kp;
            v = w0[((size_t)l * FCIN + orig) * HD + col];
        }
        w0f[i] = (short)f2bf(v);
        return;
    }
    i -= SZ0;
    if (i < 2 * SZ12) {
        const float* W = (i < SZ12) ? w1 : w2;
        short* Wf = (i < SZ12) ? w1f : w2f;
        int ii = (i < SZ12) ? i : i - SZ12;
        int j = ii & 7, t = ii >> 3;
        int lane = t & 63; t >>= 6;
        int nf = t & 3; t >>= 2;
        int kk = t & 1, l = t >> 1;
        int kp = kk * 32 + (lane >> 4) * 8 + j;
        int col = nf * 16 + (lane & 15);
        Wf[ii] = (short)f2bf(W[((size_t)l * HD + kp) * HD + col]);
    }
}

__global__ void k_init_xi(const int* __restrict__ species,
                          const float* __restrict__ Wsp,
                          float* __restrict__ xi) {
    int i = blockIdx.x * blockDim.x + threadIdx.x;
    if (i >= N_NODES * DIM) return;
    int n = i >> 6, d = i & 63;
    xi[i] = Wsp[species[n] * DIM + d];
}

// h for layer 0 (runs once): si -> cat[:,640:656] bf16, pad 656..671 = 0, mi -> mi16
__global__ void k_h0(const float* __restrict__ xi,
                     const float* __restrict__ Wsm, const float* __restrict__ bsm,
                     unsigned short* __restrict__ cat,
                     unsigned short* __restrict__ mi16) {
    int i = blockIdx.x * blockDim.x + threadIdx.x;
    if (i >= N_NODES * 2 * SUB) return;
    int n = i >> 5, j = i & 31;
    const float* xr = xi + n * DIM;
    float v = bsm[j];
    #pragma unroll
    for (int d = 0; d < DIM; ++d) v = fmaf(xr[d], Wsm[d * 2 * SUB + j], v);
    if (j < SUB) {
        cat[(size_t)n * KPAD + 640 + j] = f2bf(v);
    } else {
        mi16[n * SUB + (j - SUB)] = f2bf(v);
        cat[(size_t)n * KPAD + 640 + j] = 0;   // pad col 656..671
    }
}

// --- per-layer kernels ------------------------------------------------------

// MFMA aggregation (unchanged from round 9, minus si/pad writes).
__global__ __launch_bounds__(256) void k_agg(
    const int* __restrict__ rowptr, const int* __restrict__ edst,
    const unsigned short* __restrict__ uT,
    const unsigned short* __restrict__ mi16,
    unsigned short* __restrict__ cat)
{
    __shared__ unsigned short m_s[4][32][16];   // 4 KB, one [32][16] per wave
    const int lane = threadIdx.x & 63;
    const int w = threadIdx.x >> 6;
    const int x = lane & 15, g = lane >> 4;
    const int er = lane >> 1, half = lane & 1;

    for (int nn = 0; nn < 2; ++nn) {
        const int n = blockIdx.x * 8 + 2 * w + nn;
        const int lo = rowptr[n], hi = rowptr[n + 1];
        float4v acc0 = {0.f,0.f,0.f,0.f};
        float4v acc1 = {0.f,0.f,0.f,0.f};
        float4v acc2 = {0.f,0.f,0.f,0.f};

        for (int ba = lo & ~31; ba < hi; ba += 32) {
            asm volatile("s_waitcnt lgkmcnt(0)" ::: "memory");
            {
                int e = min(ba + er, N_EDGES - 1);
                int dst = edst[e];
                uint4 v = *(const uint4*)(mi16 + (size_t)dst * 16 + half * 8);
                *(uint4*)&m_s[w][er][half * 8] = v;
            }
            asm volatile("s_waitcnt lgkmcnt(0)" ::: "memory");

            const int klo = lo - ba;
            const int khi = hi - ba;
            short8 bq;
            if (klo <= 0 && khi >= 32) {
                #pragma unroll
                for (int j = 0; j < 8; ++j) bq[j] = (short)m_s[w][g * 8 + j][x];
            } else {
                #pragma unroll
                for (int j = 0; j < 8; ++j) {
                    int k = g * 8 + j;
                    bq[j] = (k >= klo && k < khi) ? (short)m_s[w][k][x] : (short)0;
                }
            }

            const unsigned short* ap = uT + (size_t)x * E_PAD + ba + g * 8;
            short8 a0 = *(const short8*)(ap);
            short8 a1 = *(const short8*)(ap + (size_t)16 * E_PAD);
            short8 a2 = *(const short8*)(ap + (size_t)32 * E_PAD);
            acc0 = __builtin_amdgcn_mfma_f32_16x16x32_bf16(a0, bq, acc0, 0, 0, 0);
            acc1 = __builtin_amdgcn_mfma_f32_16x16x32_bf16(a1, bq, acc1, 0, 0, 0);
            acc2 = __builtin_amdgcn_mfma_f32_16x16x32_bf16(a2, bq, acc2, 0, 0, 0);
        }

        unsigned short* cp = cat + (size_t)n * KPAD;
        #pragma unroll
        for (int i = 0; i < 4; ++i) {
            int p = g * 4 + i;
            cp[(p >> 2) * 64 + (p & 3) * 16 + x] = f2bf(acc0[i]);
        }
        #pragma unroll
        for (int i = 0; i < 4; ++i) {
            int p = 16 + g * 4 + i;
            cp[(p >> 2) * 64 + (p & 3) * 16 + x] = f2bf(acc1[i]);
        }
        if (g < 2) {
            #pragma unroll
            for (int i = 0; i < 4; ++i) {
                int p = 32 + g * 4 + i;
                cp[(p >> 2) * 64 + (p & 3) * 16 + x] = f2bf(acc2[i]);
            }
        }
    }
}

// Fused MFMA MLP + next-layer h epilogue. 16 nodes/block, 4 waves.
// fc0/fc1/fc2 identical to round 9; epilogue stages fresh xi rows in LDS and
// computes h(l+1) in exact fp32 (same math as k_h0), writing si->cat, mi->mi16.
__global__ __launch_bounds__(256) void k_mlp(
    unsigned short* cat,                       // A-frags read + si write (no alias issues: block-local)
    const short* __restrict__ w0f, const float* __restrict__ b0,
    const short* __restrict__ w1f, const float* __restrict__ b1,
    const short* __restrict__ w2f, const float* __restrict__ b2,
    const float* __restrict__ Wsm, const float* __restrict__ bsm,
    unsigned short* __restrict__ mi16,
    float* __restrict__ xi, int l)
{
    __shared__ __align__(16) unsigned short h1[16][72];
    __shared__ __align__(16) unsigned short h2[16][72];
    __shared__ float xi_s[16][68];
    const int lane = threadIdx.x & 63;
    const int w = threadIdx.x >> 6;
    const int n0 = blockIdx.x * 16;
    const int r = lane & 15, g = lane >> 4;

    // fc0: K=672, 21 MFMA steps split into 2 independent chains
    const short* Ap = (const short*)cat + (size_t)(n0 + r) * KPAD + g * 8;
    const short* Bp = w0f + ((size_t)l * NKK * 256 + w * 64 + lane) * 8;
    float bv = b0[l * HD + w * 16 + r];
    float4v accA = {bv, bv, bv, bv};
    float4v accB = {0.f, 0.f, 0.f, 0.f};
    #pragma unroll 5
    for (int kk = 0; kk < 20; kk += 2) {
        short8 aA = *(const short8*)(Ap + kk * 32);
        short8 bA = *(const short8*)(Bp + (size_t)kk * 2048);
        accA = __builtin_amdgcn_mfma_f32_16x16x32_bf16(aA, bA, accA, 0, 0, 0);
        short8 aB = *(const short8*)(Ap + (kk + 1) * 32);
        short8 bB = *(const short8*)(Bp + (size_t)(kk + 1) * 2048);
        accB = __builtin_amdgcn_mfma_f32_16x16x32_bf16(aB, bB, accB, 0, 0, 0);
    }
    {
        short8 a = *(const short8*)(Ap + 20 * 32);
        short8 b = *(const short8*)(Bp + (size_t)20 * 2048);
        accA = __builtin_amdgcn_mfma_f32_16x16x32_bf16(a, b, accA, 0, 0, 0);
    }
    #pragma unroll
    for (int i = 0; i < 4; ++i)
        h1[g * 4 + i][w * 16 + r] = f2bf(ssp(accA[i] + accB[i]));
    __syncthreads();

    // fc1
    bv = b1[l * HD + w * 16 + r];
    float4v acc1 = {bv, bv, bv, bv};
    #pragma unroll
    for (int kk = 0; kk < 2; ++kk) {
        short8 a = *(const short8*)((const short*)&h1[r][kk * 32 + g * 8]);
        short8 b = *(const short8*)(w1f + ((size_t)(l * 2 + kk) * 256 + w * 64 + lane) * 8);
        acc1 = __builtin_amdgcn_mfma_f32_16x16x32_bf16(a, b, acc1, 0, 0, 0);
    }
    #pragma unroll
    for (int i = 0; i < 4; ++i)
        h2[g * 4 + i][w * 16 + r] = f2bf(ssp(acc1[i]));
    __syncthreads();

    // fc2 + residual; stage fresh xi rows into LDS for the h epilogue
    bv = b2[l * DIM + w * 16 + r];
    float4v acc2 = {bv, bv, bv, bv};
    #pragma unroll
    for (int kk = 0; kk < 2; ++kk) {
        short8 a = *(const short8*)((const short*)&h2[r][kk * 32 + g * 8]);
        short8 b = *(const short8*)(w2f + ((size_t)(l * 2 + kk) * 256 + w * 64 + lane) * 8);
        acc2 = __builtin_amdgcn_mfma_f32_16x16x32_bf16(a, b, acc2, 0, 0, 0);
    }
    #pragma unroll
    for (int i = 0; i < 4; ++i) {
        size_t idx = (size_t)(n0 + g * 4 + i) * DIM + w * 16 + r;
        float nv = xi[idx] + acc2[i];
        xi[idx] = nv;
        xi_s[g * 4 + i][w * 16 + r] = nv;
    }

    // h(l+1) epilogue: exact fp32, 2 (node,j) pairs per thread
    if (l + 1 < LAYERS) {
        __syncthreads();
        const float* W  = Wsm + (size_t)(l + 1) * DIM * 2 * SUB;
        const float* bs = bsm + (l + 1) * 2 * SUB;
        #pragma unroll
        for (int pp = 0; pp < 2; ++pp) {
            int pair = threadIdx.x + pp * 256;
            int nl = pair >> 5, j = pair & 31;
            float v = bs[j];
            const float* xr = &xi_s[nl][0];
            #pragma unroll 8
            for (int d = 0; d < DIM; ++d) v = fmaf(xr[d], W[d * 2 * SUB + j], v);
            int n = n0 + nl;
            if (j < SUB) {
                cat[(size_t)n * KPAD + 640 + j] = f2bf(v);
            } else {
                mi16[n * SUB + (j - SUB)] = f2bf(v);
                cat[(size_t)n * KPAD + 640 + j] = 0;   // pad col
            }
        }
    }
}

extern "C" void kernel_launch(void* const* d_in, const int* in_sizes, int n_in,
                              void* d_out, int out_size, void* d_ws, size_t ws_size,
                              hipStream_t stream) {
    const int*   species = (const int*)  d_in[0];
    const int*   esrc    = (const int*)  d_in[1];
    const int*   edst    = (const int*)  d_in[2];
    const float* dist    = (const float*)d_in[3];
    const float* sw      = (const float*)d_in[4];
    const float* bo      = (const float*)d_in[5];
    const float* Wsp     = (const float*)d_in[6];
    const float* Wsm     = (const float*)d_in[7];
    const float* bsm     = (const float*)d_in[8];
    const float* w0      = (const float*)d_in[9];
    const float* b0      = (const float*)d_in[10];
    const float* w1      = (const float*)d_in[11];
    const float* b1      = (const float*)d_in[12];
    const float* w2      = (const float*)d_in[13];
    const float* b2      = (const float*)d_in[14];

    float* xi = (float*)d_out;   // N x 64 fp32, updated in place

    // ws layout: uT 48*E_PAD ush | mi16 N*16 ush | cat N*672 ush | w0f | w1f | w2f | rowptr
    unsigned short* uT    = (unsigned short*)d_ws;
    unsigned short* mi16  = uT + (size_t)48 * E_PAD;
    unsigned short* cat   = mi16 + (size_t)N_NODES * SUB;
    short* w0f = (short*)(cat + (size_t)N_NODES * KPAD);
    short* w1f = w0f + (size_t)LAYERS * NKK * 2048;
    short* w2f = w1f + (size_t)LAYERS * 2 * 2048;
    int* rowptr = (int*)(w2f + (size_t)LAYERS * 2 * 2048);

    k_rowptr<<<(N_NODES + 1 + 255) / 256, 256, 0, stream>>>(esrc, rowptr);
    k_u<<<(E_PAD + 255) / 256, 256, 0, stream>>>(dist, sw, bo, uT);
    {
        int total = LAYERS * NKK * 2048 + 2 * LAYERS * 2 * 2048;
        k_packw<<<(total + 255) / 256, 256, 0, stream>>>(w0, w1, w2, w0f, w1f, w2f);
    }
    k_init_xi<<<(N_NODES * DIM + 255) / 256, 256, 0, stream>>>(species, Wsp, xi);
    k_h0<<<(N_NODES * 2 * SUB + 255) / 256, 256, 0, stream>>>(xi, Wsm, bsm, cat, mi16);

    for (int l = 0; l < LAYERS; ++l) {
        k_agg<<<N_NODES / 8, 256, 0, stream>>>(rowptr, edst, uT, mi16, cat);
        k_mlp<<<N_NODES / 16, 256, 0, stream>>>(cat, w0f, b0, w1f, b1, w2f, b2,
                                                Wsm, bsm, mi16, xi, l);
    }
}

// Round 11
// 140.350 us; speedup vs baseline: 1.9481x; 1.1988x over previous
//
#include <hip/hip_runtime.h>
#include <math.h>

#define N_NODES 20000
#define N_EDGES 320000
#define E_PAD 320032               // N_EDGES + 32, multiple of 8
#define DIM 64
#define SUB 16
#define NRBF 8
#define NB 5
#define LAYERS 3
#define FCIN (NRBF*SUB*NB + SUB)   // 656
#define KPAD 672                   // 21 * 32
#define NKK 21
#define HD 64
#define CUTOFF 5.0f
#define TS 680                     // LDS cat-tile row stride (ush): 2-way banks

typedef __attribute__((ext_vector_type(8))) short short8;
typedef __attribute__((ext_vector_type(4))) float float4v;

__device__ __forceinline__ float ssp(float x) {
    float sp = fmaxf(x, 0.0f) + log1pf(expf(-fabsf(x)));
    return sp - 0.69314718055994530942f;
}

__device__ __forceinline__ unsigned short f2bf(float x) {
    unsigned int u = __float_as_uint(x);
    unsigned int r = (u + 0x7FFFu + ((u >> 16) & 1u)) >> 16;
    return (unsigned short)r;
}

// --- one-time kernels -------------------------------------------------------

__global__ void k_rowptr(const int* __restrict__ esrc, int* __restrict__ rowptr) {
    int n = blockIdx.x * blockDim.x + threadIdx.x;
    if (n > N_NODES) return;
    int a = 0, b = N_EDGES;
    while (a < b) { int m = (a + b) >> 1; if (esrc[m] < n) a = m + 1; else b = m; }
    rowptr[n] = a;
}

// uT[p][e] = bf16( sw[e] * rb[p/5] * bo[e][p%5] ) for p<40; rows 40..47 zero.
__global__ void k_u(const float* __restrict__ dist, const float* __restrict__ sw,
                    const float* __restrict__ bo, unsigned short* __restrict__ uT) {
    int e = blockIdx.x * blockDim.x + threadIdx.x;
    if (e >= E_PAD) return;
    bool oke = e < N_EDGES;
    float d  = oke ? dist[e] : 0.0f;
    float s  = oke ? sw[e]   : 0.0f;
    float rbv[NRBF], bov[NB];
    #pragma unroll
    for (int r = 0; r < NRBF; ++r) {
        float mu = (CUTOFF / (NRBF - 1)) * (float)r;
        float z = (d - mu) * ((float)NRBF / CUTOFF);
        rbv[r] = s * expf(-0.5f * z * z);
    }
    #pragma unroll
    for (int b = 0; b < NB; ++b) bov[b] = oke ? bo[e * NB + b] : 0.0f;
    #pragma unroll
    for (int p = 0; p < 48; ++p) {
        float v = (p < 40) ? rbv[p / 5] * bov[p % 5] : 0.0f;
        uT[(size_t)p * E_PAD + e] = f2bf(v);
    }
}

// Pack weights into MFMA B-fragment order (bf16). Same layout as round 3.
__global__ void k_packw(const float* __restrict__ w0, const float* __restrict__ w1,
                        const float* __restrict__ w2,
                        short* __restrict__ w0f, short* __restrict__ w1f,
                        short* __restrict__ w2f) {
    int i = blockIdx.x * blockDim.x + threadIdx.x;
    const int SZ0 = LAYERS * NKK * 4 * 64 * 8;       // 129024
    const int SZ12 = LAYERS * 2 * 4 * 64 * 8;        // 12288
    if (i < SZ0) {
        int j = i & 7, t = i >> 3;
        int lane = t & 63; t >>= 6;
        int nf = t & 3; t >>= 2;
        int kk = t % NKK, l = t / NKK;
        int kp = kk * 32 + (lane >> 4) * 8 + j;
        int col = nf * 16 + (lane & 15);
        float v = 0.0f;
        if (kp < FCIN) {
            int orig;
            if (kp < 640) {
                int j10 = kp >> 6, rem = kp & 63, g = rem >> 4, s = rem & 15;
                int p = g + 4 * j10;
                orig = (p / 5) * 80 + s * 5 + (p - 5 * (p / 5));
            } else orig = kp;
            v = w0[((size_t)l * FCIN + orig) * HD + col];
        }
        w0f[i] = (short)f2bf(v);
        return;
    }
    i -= SZ0;
    if (i < 2 * SZ12) {
        const float* W = (i < SZ12) ? w1 : w2;
        short* Wf = (i < SZ12) ? w1f : w2f;
        int ii = (i < SZ12) ? i : i - SZ12;
        int j = ii & 7, t = ii >> 3;
        int lane = t & 63; t >>= 6;
        int nf = t & 3; t >>= 2;
        int kk = t & 1, l = t >> 1;
        int kp = kk * 32 + (lane >> 4) * 8 + j;
        int col = nf * 16 + (lane & 15);
        Wf[ii] = (short)f2bf(W[((size_t)l * HD + kp) * HD + col]);
    }
}

__global__ void k_init_xi(const int* __restrict__ species,
                          const float* __restrict__ Wsp,
                          float* __restrict__ xi) {
    int i = blockIdx.x * blockDim.x + threadIdx.x;
    if (i >= N_NODES * DIM) return;
    int n = i >> 6, d = i & 63;
    xi[i] = Wsp[species[n] * DIM + d];
}

// h for layer 0 (runs once): si -> si16 (bf16), mi -> mi buffer 0 (bf16)
__global__ void k_h0(const float* __restrict__ xi,
                     const float* __restrict__ Wsm, const float* __restrict__ bsm,
                     unsigned short* __restrict__ si16,
                     unsigned short* __restrict__ mi16) {
    int i = blockIdx.x * blockDim.x + threadIdx.x;
    if (i >= N_NODES * 2 * SUB) return;
    int n = i >> 5, j = i & 31;
    const float* xr = xi + n * DIM;
    float v = bsm[j];
    #pragma unroll
    for (int d = 0; d < DIM; ++d) v = fmaf(xr[d], Wsm[d * 2 * SUB + j], v);
    if (j < SUB) si16[n * SUB + j] = f2bf(v);
    else         mi16[n * SUB + (j - SUB)] = f2bf(v);
}

// --- fused per-layer kernel -------------------------------------------------
// Block = 16 nodes, 4 waves.
// Phase A (agg, round-9 MFMA scheme): wave w -> nodes n0+4w..n0+4w+3, C frags
//   written to LDS cat tile (stride TS=680: 2-way banks only). si from si16.
// Phase B (MLP, round-10): fc0 A-frags from LDS tile; fc1/fc2; residual;
//   h(l+1) epilogue -> si16 + mi_wr (double-buffered vs the gathered mi_rd).
__global__ __launch_bounds__(256) void k_layer(
    const int* __restrict__ rowptr, const int* __restrict__ edst,
    const unsigned short* __restrict__ uT,
    const unsigned short* __restrict__ mi_rd,
    unsigned short* __restrict__ mi_wr,
    unsigned short* __restrict__ si16,
    const short* __restrict__ w0f, const float* __restrict__ b0,
    const short* __restrict__ w1f, const float* __restrict__ b1,
    const short* __restrict__ w2f, const float* __restrict__ b2,
    const float* __restrict__ Wsm, const float* __restrict__ bsm,
    float* __restrict__ xi, int l)
{
    __shared__ __align__(16) unsigned short tile[16][TS];    // 21760 B
    __shared__ __align__(16) unsigned char scratch[8960];    // union
    unsigned short (*m_s)[32][16] = (unsigned short (*)[32][16])scratch; // agg
    unsigned short (*h1)[72] = (unsigned short (*)[72])scratch;          // mlp
    unsigned short (*h2)[72] = (unsigned short (*)[72])(scratch + 2304);
    float (*xi_s)[68] = (float (*)[68])(scratch + 4608);

    const int lane = threadIdx.x & 63;
    const int w = threadIdx.x >> 6;
    const int n0 = blockIdx.x * 16;
    const int x = lane & 15, g = lane >> 4;
    const int er = lane >> 1, half = lane & 1;

    // ---- Phase A: MFMA aggregation into LDS tile ----
    for (int nn = 0; nn < 4; ++nn) {
        const int n = n0 + 4 * w + nn;
        const int lo = rowptr[n], hi = rowptr[n + 1];
        float4v acc0 = {0.f,0.f,0.f,0.f};
        float4v acc1 = {0.f,0.f,0.f,0.f};
        float4v acc2 = {0.f,0.f,0.f,0.f};

        for (int ba = lo & ~31; ba < hi; ba += 32) {
            asm volatile("s_waitcnt lgkmcnt(0)" ::: "memory");
            {
                int e = min(ba + er, N_EDGES - 1);
                int dst = edst[e];
                uint4 v = *(const uint4*)(mi_rd + (size_t)dst * 16 + half * 8);
                *(uint4*)&m_s[w][er][half * 8] = v;
            }
            asm volatile("s_waitcnt lgkmcnt(0)" ::: "memory");

            const int klo = lo - ba;
            const int khi = hi - ba;
            short8 bq;
            if (klo <= 0 && khi >= 32) {
                #pragma unroll
                for (int j = 0; j < 8; ++j) bq[j] = (short)m_s[w][g * 8 + j][x];
            } else {
                #pragma unroll
                for (int j = 0; j < 8; ++j) {
                    int k = g * 8 + j;
                    bq[j] = (k >= klo && k < khi) ? (short)m_s[w][k][x] : (short)0;
                }
            }

            const unsigned short* ap = uT + (size_t)x * E_PAD + ba + g * 8;
            short8 a0 = *(const short8*)(ap);
            short8 a1 = *(const short8*)(ap + (size_t)16 * E_PAD);
            short8 a2 = *(const short8*)(ap + (size_t)32 * E_PAD);
            acc0 = __builtin_amdgcn_mfma_f32_16x16x32_bf16(a0, bq, acc0, 0, 0, 0);
            acc1 = __builtin_amdgcn_mfma_f32_16x16x32_bf16(a1, bq, acc1, 0, 0, 0);
            acc2 = __builtin_amdgcn_mfma_f32_16x16x32_bf16(a2, bq, acc2, 0, 0, 0);
        }

        const int row = 4 * w + nn;
        unsigned short* tp = &tile[row][0];
        #pragma unroll
        for (int i = 0; i < 4; ++i) {
            int p = g * 4 + i;
            tp[(p >> 2) * 64 + (p & 3) * 16 + x] = f2bf(acc0[i]);
        }
        #pragma unroll
        for (int i = 0; i < 4; ++i) {
            int p = 16 + g * 4 + i;
            tp[(p >> 2) * 64 + (p & 3) * 16 + x] = f2bf(acc1[i]);
        }
        if (g < 2) {
            #pragma unroll
            for (int i = 0; i < 4; ++i) {
                int p = 32 + g * 4 + i;
                tp[(p >> 2) * 64 + (p & 3) * 16 + x] = f2bf(acc2[i]);
            }
        }
        if (lane < SUB)      tp[640 + lane] = si16[(size_t)n * SUB + lane];
        else if (lane < 32)  tp[640 + lane] = 0;   // pad cols 656..671
    }
    __syncthreads();

    // ---- Phase B: MFMA MLP (A-frags from LDS tile) ----
    const int r = x;
    const short* Bp = w0f + ((size_t)l * NKK * 256 + w * 64 + lane) * 8;
    float bv = b0[l * HD + w * 16 + r];
    float4v accA = {bv, bv, bv, bv};
    float4v accB = {0.f, 0.f, 0.f, 0.f};
    #pragma unroll 5
    for (int kk = 0; kk < 20; kk += 2) {
        short8 aA = *(const short8*)((const short*)&tile[r][kk * 32 + g * 8]);
        short8 bA = *(const short8*)(Bp + (size_t)kk * 2048);
        accA = __builtin_amdgcn_mfma_f32_16x16x32_bf16(aA, bA, accA, 0, 0, 0);
        short8 aB = *(const short8*)((const short*)&tile[r][(kk + 1) * 32 + g * 8]);
        short8 bB = *(const short8*)(Bp + (size_t)(kk + 1) * 2048);
        accB = __builtin_amdgcn_mfma_f32_16x16x32_bf16(aB, bB, accB, 0, 0, 0);
    }
    {
        short8 a = *(const short8*)((const short*)&tile[r][20 * 32 + g * 8]);
        short8 b = *(const short8*)(Bp + (size_t)20 * 2048);
        accA = __builtin_amdgcn_mfma_f32_16x16x32_bf16(a, b, accA, 0, 0, 0);
    }
    __syncthreads();   // tile reads done before scratch (h1) overwrite
    #pragma unroll
    for (int i = 0; i < 4; ++i)
        h1[g * 4 + i][w * 16 + r] = f2bf(ssp(accA[i] + accB[i]));
    __syncthreads();

    // fc1
    bv = b1[l * HD + w * 16 + r];
    float4v acc1v = {bv, bv, bv, bv};
    #pragma unroll
    for (int kk = 0; kk < 2; ++kk) {
        short8 a = *(const short8*)((const short*)&h1[r][kk * 32 + g * 8]);
        short8 b = *(const short8*)(w1f + ((size_t)(l * 2 + kk) * 256 + w * 64 + lane) * 8);
        acc1v = __builtin_amdgcn_mfma_f32_16x16x32_bf16(a, b, acc1v, 0, 0, 0);
    }
    __syncthreads();
    #pragma unroll
    for (int i = 0; i < 4; ++i)
        h2[g * 4 + i][w * 16 + r] = f2bf(ssp(acc1v[i]));
    __syncthreads();

    // fc2 + residual; stage fresh xi rows for the h epilogue
    bv = b2[l * DIM + w * 16 + r];
    float4v acc2v = {bv, bv, bv, bv};
    #pragma unroll
    for (int kk = 0; kk < 2; ++kk) {
        short8 a = *(const short8*)((const short*)&h2[r][kk * 32 + g * 8]);
        short8 b = *(const short8*)(w2f + ((size_t)(l * 2 + kk) * 256 + w * 64 + lane) * 8);
        acc2v = __builtin_amdgcn_mfma_f32_16x16x32_bf16(a, b, acc2v, 0, 0, 0);
    }
    #pragma unroll
    for (int i = 0; i < 4; ++i) {
        size_t idx = (size_t)(n0 + g * 4 + i) * DIM + w * 16 + r;
        float nv = xi[idx] + acc2v[i];
        xi[idx] = nv;
        xi_s[g * 4 + i][w * 16 + r] = nv;
    }

    // h(l+1) epilogue: exact fp32 (same math as k_h0)
    if (l + 1 < LAYERS) {
        __syncthreads();
        const float* W  = Wsm + (size_t)(l + 1) * DIM * 2 * SUB;
        const float* bs = bsm + (l + 1) * 2 * SUB;
        #pragma unroll
        for (int pp = 0; pp < 2; ++pp) {
            int pair = threadIdx.x + pp * 256;
            int nl = pair >> 5, j = pair & 31;
            float v = bs[j];
            const float* xr = &xi_s[nl][0];
            #pragma unroll 8
            for (int d = 0; d < DIM; ++d) v = fmaf(xr[d], W[d * 2 * SUB + j], v);
            int n = n0 + nl;
            if (j < SUB) si16[(size_t)n * SUB + j] = f2bf(v);
            else         mi_wr[(size_t)n * SUB + (j - SUB)] = f2bf(v);
        }
    }
}

extern "C" void kernel_launch(void* const* d_in, const int* in_sizes, int n_in,
                              void* d_out, int out_size, void* d_ws, size_t ws_size,
                              hipStream_t stream) {
    const int*   species = (const int*)  d_in[0];
    const int*   esrc    = (const int*)  d_in[1];
    const int*   edst    = (const int*)  d_in[2];
    const float* dist    = (const float*)d_in[3];
    const float* sw      = (const float*)d_in[4];
    const float* bo      = (const float*)d_in[5];
    const float* Wsp     = (const float*)d_in[6];
    const float* Wsm     = (const float*)d_in[7];
    const float* bsm     = (const float*)d_in[8];
    const float* w0      = (const float*)d_in[9];
    const float* b0      = (const float*)d_in[10];
    const float* w1      = (const float*)d_in[11];
    const float* b1      = (const float*)d_in[12];
    const float* w2      = (const float*)d_in[13];
    const float* b2      = (const float*)d_in[14];

    float* xi = (float*)d_out;   // N x 64 fp32, updated in place

    // ws layout: uT 48*E_PAD ush | mi16 2 x N*16 ush | si16 N*16 ush |
    //            w0f | w1f | w2f | rowptr
    unsigned short* uT    = (unsigned short*)d_ws;
    unsigned short* mi0   = uT + (size_t)48 * E_PAD;
    unsigned short* mi1   = mi0 + (size_t)N_NODES * SUB;
    unsigned short* si16  = mi1 + (size_t)N_NODES * SUB;
    short* w0f = (short*)(si16 + (size_t)N_NODES * SUB);
    short* w1f = w0f + (size_t)LAYERS * NKK * 2048;
    short* w2f = w1f + (size_t)LAYERS * 2 * 2048;
    int* rowptr = (int*)(w2f + (size_t)LAYERS * 2 * 2048);

    k_rowptr<<<(N_NODES + 1 + 255) / 256, 256, 0, stream>>>(esrc, rowptr);
    k_u<<<(E_PAD + 255) / 256, 256, 0, stream>>>(dist, sw, bo, uT);
    {
        int total = LAYERS * NKK * 2048 + 2 * LAYERS * 2 * 2048;
        k_packw<<<(total + 255) / 256, 256, 0, stream>>>(w0, w1, w2, w0f, w1f, w2f);
    }
    k_init_xi<<<(N_NODES * DIM + 255) / 256, 256, 0, stream>>>(species, Wsp, xi);
    k_h0<<<(N_NODES * 2 * SUB + 255) / 256, 256, 0, stream>>>(xi, Wsm, bsm, si16, mi0);

    for (int l = 0; l < LAYERS; ++l) {
        unsigned short* mi_rd = (l & 1) ? mi1 : mi0;
        unsigned short* mi_wr = (l & 1) ? mi0 : mi1;
        k_layer<<<N_NODES / 16, 256, 0, stream>>>(rowptr, edst, uT, mi_rd, mi_wr,
                                                  si16, w0f, b0, w1f, b1, w2f, b2,
                                                  Wsm, bsm, xi, l);
    }
}

// Round 12
// 131.785 us; speedup vs baseline: 2.0747x; 1.0650x over previous
//
#include <hip/hip_runtime.h>
#include <math.h>

#define N_NODES 20000
#define N_EDGES 320000
#define E_PAD 320032               // N_EDGES + 32, multiple of 8
#define DIM 64
#define SUB 16
#define NRBF 8
#define NB 5
#define LAYERS 3
#define FCIN (NRBF*SUB*NB + SUB)   // 656
#define KPAD 672                   // 21 * 32
#define NKK 21
#define HD 64
#define CUTOFF 5.0f
#define TS 680                     // LDS cat-tile row stride (ush): 2-way banks

typedef __attribute__((ext_vector_type(8))) short short8;
typedef __attribute__((ext_vector_type(4))) float float4v;

__device__ __forceinline__ float ssp(float x) {
    float sp = fmaxf(x, 0.0f) + log1pf(expf(-fabsf(x)));
    return sp - 0.69314718055994530942f;
}

__device__ __forceinline__ unsigned short f2bf(float x) {
    unsigned int u = __float_as_uint(x);
    unsigned int r = (u + 0x7FFFu + ((u >> 16) & 1u)) >> 16;
    return (unsigned short)r;
}

// --- one-time kernels -------------------------------------------------------

__global__ void k_rowptr(const int* __restrict__ esrc, int* __restrict__ rowptr) {
    int n = blockIdx.x * blockDim.x + threadIdx.x;
    if (n > N_NODES) return;
    int a = 0, b = N_EDGES;
    while (a < b) { int m = (a + b) >> 1; if (esrc[m] < n) a = m + 1; else b = m; }
    rowptr[n] = a;
}

// uT[p][e] = bf16( sw[e] * rb[p/5] * bo[e][p%5] ) for p<40; rows 40..47 zero.
__global__ void k_u(const float* __restrict__ dist, const float* __restrict__ sw,
                    const float* __restrict__ bo, unsigned short* __restrict__ uT) {
    int e = blockIdx.x * blockDim.x + threadIdx.x;
    if (e >= E_PAD) return;
    bool oke = e < N_EDGES;
    float d  = oke ? dist[e] : 0.0f;
    float s  = oke ? sw[e]   : 0.0f;
    float rbv[NRBF], bov[NB];
    #pragma unroll
    for (int r = 0; r < NRBF; ++r) {
        float mu = (CUTOFF / (NRBF - 1)) * (float)r;
        float z = (d - mu) * ((float)NRBF / CUTOFF);
        rbv[r] = s * expf(-0.5f * z * z);
    }
    #pragma unroll
    for (int b = 0; b < NB; ++b) bov[b] = oke ? bo[e * NB + b] : 0.0f;
    #pragma unroll
    for (int p = 0; p < 48; ++p) {
        float v = (p < 40) ? rbv[p / 5] * bov[p % 5] : 0.0f;
        uT[(size_t)p * E_PAD + e] = f2bf(v);
    }
}

// Pack weights into MFMA B-fragment order (bf16). Same layout as round 3.
__global__ void k_packw(const float* __restrict__ w0, const float* __restrict__ w1,
                        const float* __restrict__ w2,
                        short* __restrict__ w0f, short* __restrict__ w1f,
                        short* __restrict__ w2f) {
    int i = blockIdx.x * blockDim.x + threadIdx.x;
    const int SZ0 = LAYERS * NKK * 4 * 64 * 8;       // 129024
    const int SZ12 = LAYERS * 2 * 4 * 64 * 8;        // 12288
    if (i < SZ0) {
        int j = i & 7, t = i >> 3;
        int lane = t & 63; t >>= 6;
        int nf = t & 3; t >>= 2;
        int kk = t % NKK, l = t / NKK;
        int kp = kk * 32 + (lane >> 4) * 8 + j;
        int col = nf * 16 + (lane & 15);
        float v = 0.0f;
        if (kp < FCIN) {
            int orig;
            if (kp < 640) {
                int j10 = kp >> 6, rem = kp & 63, g = rem >> 4, s = rem & 15;
                int p = g + 4 * j10;
                orig = (p / 5) * 80 + s * 5 + (p - 5 * (p / 5));
            } else orig = kp;
            v = w0[((size_t)l * FCIN + orig) * HD + col];
        }
        w0f[i] = (short)f2bf(v);
        return;
    }
    i -= SZ0;
    if (i < 2 * SZ12) {
        const float* W = (i < SZ12) ? w1 : w2;
        short* Wf = (i < SZ12) ? w1f : w2f;
        int ii = (i < SZ12) ? i : i - SZ12;
        int j = ii & 7, t = ii >> 3;
        int lane = t & 63; t >>= 6;
        int nf = t & 3; t >>= 2;
        int kk = t & 1, l = t >> 1;
        int kp = kk * 32 + (lane >> 4) * 8 + j;
        int col = nf * 16 + (lane & 15);
        Wf[ii] = (short)f2bf(W[((size_t)l * HD + kp) * HD + col]);
    }
}

// Fused init: xi = W_species[species]; h(0) -> si16 + mi0. 8 nodes/block.
__global__ __launch_bounds__(256) void k_init(
    const int* __restrict__ species, const float* __restrict__ Wsp,
    const float* __restrict__ Wsm, const float* __restrict__ bsm,
    float* __restrict__ xi,
    unsigned short* __restrict__ si16, unsigned short* __restrict__ mi16) {
    __shared__ float xs[8][64];
    const int nl = threadIdx.x >> 5, j = threadIdx.x & 31;
    const int n = blockIdx.x * 8 + nl;
    const int sp = species[n];
    float v0 = Wsp[sp * DIM + j];
    float v1 = Wsp[sp * DIM + 32 + j];
    xi[(size_t)n * DIM + j] = v0;
    xi[(size_t)n * DIM + 32 + j] = v1;
    xs[nl][j] = v0;
    xs[nl][32 + j] = v1;
    __syncthreads();
    float v = bsm[j];
    const float* xr = &xs[nl][0];
    #pragma unroll 8
    for (int d = 0; d < DIM; ++d) v = fmaf(xr[d], Wsm[d * 2 * SUB + j], v);
    if (j < SUB) si16[(size_t)n * SUB + j] = f2bf(v);
    else         mi16[(size_t)n * SUB + (j - SUB)] = f2bf(v);
}

// --- fused per-layer kernel -------------------------------------------------
// Block = 16 nodes, 4 waves.
// Phase A: MFMA aggregation, B-fragment gathered DIRECTLY into VGPRs (no LDS,
//   no wave-sync drains -> compiler pipelines across chunks and nodes).
// Phase B: fc0 (A from LDS tile) -> fc1 -> fc2 + residual -> h(l+1) epilogue.
// h1/h2/xi_s overlay the tile (dead after fc0) -> LDS = 21.8 KB only.
__global__ __launch_bounds__(256) void k_layer(
    const int* __restrict__ rowptr, const int* __restrict__ edst,
    const unsigned short* __restrict__ uT,
    const unsigned short* __restrict__ mi_rd,
    unsigned short* __restrict__ mi_wr,
    unsigned short* __restrict__ si16,
    const short* __restrict__ w0f, const float* __restrict__ b0,
    const short* __restrict__ w1f, const float* __restrict__ b1,
    const short* __restrict__ w2f, const float* __restrict__ b2,
    const float* __restrict__ Wsm, const float* __restrict__ bsm,
    float* __restrict__ xi, int l)
{
    __shared__ __align__(16) unsigned short tile[16][TS];    // 21760 B total LDS
    unsigned short (*h1)[72] = (unsigned short (*)[72])((char*)tile);          // 2304 B
    unsigned short (*h2)[72] = (unsigned short (*)[72])((char*)tile + 4608);   // 2304 B
    float (*xi_s)[68]        = (float (*)[68])((char*)tile + 9216);            // 4352 B

    const int lane = threadIdx.x & 63;
    const int w = threadIdx.x >> 6;
    const int n0 = blockIdx.x * 16;
    const int x = lane & 15, g = lane >> 4;

    // ---- Phase A: MFMA aggregation into LDS tile, B-frags via VGPR gather ----
    const unsigned short* mx = mi_rd + x;
    for (int nn = 0; nn < 4; ++nn) {
        const int n = n0 + 4 * w + nn;
        const int lo = rowptr[n], hi = rowptr[n + 1];
        float4v acc0 = {0.f,0.f,0.f,0.f};
        float4v acc1 = {0.f,0.f,0.f,0.f};
        float4v acc2 = {0.f,0.f,0.f,0.f};

        for (int ba = lo & ~31; ba < hi; ba += 32) {
            // dst indices for this lane's k-slice (k = g*8+j); N_EDGES % 32 == 0
            int4 i0 = *(const int4*)(edst + ba + g * 8);
            int4 i1 = *(const int4*)(edst + ba + g * 8 + 4);
            // gather mi values (unconditional; masked after)
            unsigned short v0 = mx[(size_t)i0.x * 16];
            unsigned short v1 = mx[(size_t)i0.y * 16];
            unsigned short v2 = mx[(size_t)i0.z * 16];
            unsigned short v3 = mx[(size_t)i0.w * 16];
            unsigned short v4 = mx[(size_t)i1.x * 16];
            unsigned short v5 = mx[(size_t)i1.y * 16];
            unsigned short v6 = mx[(size_t)i1.z * 16];
            unsigned short v7 = mx[(size_t)i1.w * 16];
            const int klo = lo - ba, khi = hi - ba;
            const int kb = g * 8;
            short8 bq;
            bq[0] = (kb+0 >= klo && kb+0 < khi) ? (short)v0 : (short)0;
            bq[1] = (kb+1 >= klo && kb+1 < khi) ? (short)v1 : (short)0;
            bq[2] = (kb+2 >= klo && kb+2 < khi) ? (short)v2 : (short)0;
            bq[3] = (kb+3 >= klo && kb+3 < khi) ? (short)v3 : (short)0;
            bq[4] = (kb+4 >= klo && kb+4 < khi) ? (short)v4 : (short)0;
            bq[5] = (kb+5 >= klo && kb+5 < khi) ? (short)v5 : (short)0;
            bq[6] = (kb+6 >= klo && kb+6 < khi) ? (short)v6 : (short)0;
            bq[7] = (kb+7 >= klo && kb+7 < khi) ? (short)v7 : (short)0;

            const unsigned short* ap = uT + (size_t)x * E_PAD + ba + g * 8;
            short8 a0 = *(const short8*)(ap);
            short8 a1 = *(const short8*)(ap + (size_t)16 * E_PAD);
            short8 a2 = *(const short8*)(ap + (size_t)32 * E_PAD);
            acc0 = __builtin_amdgcn_mfma_f32_16x16x32_bf16(a0, bq, acc0, 0, 0, 0);
            acc1 = __builtin_amdgcn_mfma_f32_16x16x32_bf16(a1, bq, acc1, 0, 0, 0);
            acc2 = __builtin_amdgcn_mfma_f32_16x16x32_bf16(a2, bq, acc2, 0, 0, 0);
        }

        const int row = 4 * w + nn;
        unsigned short* tp = &tile[row][0];
        #pragma unroll
        for (int i = 0; i < 4; ++i) {
            int p = g * 4 + i;
            tp[(p >> 2) * 64 + (p & 3) * 16 + x] = f2bf(acc0[i]);
        }
        #pragma unroll
        for (int i = 0; i < 4; ++i) {
            int p = 16 + g * 4 + i;
            tp[(p >> 2) * 64 + (p & 3) * 16 + x] = f2bf(acc1[i]);
        }
        if (g < 2) {
            #pragma unroll
            for (int i = 0; i < 4; ++i) {
                int p = 32 + g * 4 + i;
                tp[(p >> 2) * 64 + (p & 3) * 16 + x] = f2bf(acc2[i]);
            }
        }
        if (lane < SUB)      tp[640 + lane] = si16[(size_t)n * SUB + lane];
        else if (lane < 32)  tp[640 + lane] = 0;   // pad cols 656..671
    }
    __syncthreads();

    // ---- Phase B: MFMA MLP (A-frags from LDS tile) ----
    const int r = x;
    const short* Bp = w0f + ((size_t)l * NKK * 256 + w * 64 + lane) * 8;
    float bv = b0[l * HD + w * 16 + r];
    float4v accA = {bv, bv, bv, bv};
    float4v accB = {0.f, 0.f, 0.f, 0.f};
    #pragma unroll 5
    for (int kk = 0; kk < 20; kk += 2) {
        short8 aA = *(const short8*)((const short*)&tile[r][kk * 32 + g * 8]);
        short8 bA = *(const short8*)(Bp + (size_t)kk * 2048);
        accA = __builtin_amdgcn_mfma_f32_16x16x32_bf16(aA, bA, accA, 0, 0, 0);
        short8 aB = *(const short8*)((const short*)&tile[r][(kk + 1) * 32 + g * 8]);
        short8 bB = *(const short8*)(Bp + (size_t)(kk + 1) * 2048);
        accB = __builtin_amdgcn_mfma_f32_16x16x32_bf16(aB, bB, accB, 0, 0, 0);
    }
    {
        short8 a = *(const short8*)((const short*)&tile[r][20 * 32 + g * 8]);
        short8 b = *(const short8*)(Bp + (size_t)20 * 2048);
        accA = __builtin_amdgcn_mfma_f32_16x16x32_bf16(a, b, accA, 0, 0, 0);
    }
    __syncthreads();   // all tile reads done before h1 overlays it
    #pragma unroll
    for (int i = 0; i < 4; ++i)
        h1[g * 4 + i][w * 16 + r] = f2bf(ssp(accA[i] + accB[i]));
    __syncthreads();

    // fc1
    bv = b1[l * HD + w * 16 + r];
    float4v acc1v = {bv, bv, bv, bv};
    #pragma unroll
    for (int kk = 0; kk < 2; ++kk) {
        short8 a = *(const short8*)((const short*)&h1[r][kk * 32 + g * 8]);
        short8 b = *(const short8*)(w1f + ((size_t)(l * 2 + kk) * 256 + w * 64 + lane) * 8);
        acc1v = __builtin_amdgcn_mfma_f32_16x16x32_bf16(a, b, acc1v, 0, 0, 0);
    }
    #pragma unroll
    for (int i = 0; i < 4; ++i)
        h2[g * 4 + i][w * 16 + r] = f2bf(ssp(acc1v[i]));   // h2 disjoint from h1
    __syncthreads();

    // fc2 + residual; stage fresh xi rows for the h epilogue
    bv = b2[l * DIM + w * 16 + r];
    float4v acc2v = {bv, bv, bv, bv};
    #pragma unroll
    for (int kk = 0; kk < 2; ++kk) {
        short8 a = *(const short8*)((const short*)&h2[r][kk * 32 + g * 8]);
        short8 b = *(const short8*)(w2f + ((size_t)(l * 2 + kk) * 256 + w * 64 + lane) * 8);
        acc2v = __builtin_amdgcn_mfma_f32_16x16x32_bf16(a, b, acc2v, 0, 0, 0);
    }
    #pragma unroll
    for (int i = 0; i < 4; ++i) {
        size_t idx = (size_t)(n0 + g * 4 + i) * DIM + w * 16 + r;
        float nv = xi[idx] + acc2v[i];
        xi[idx] = nv;
        xi_s[g * 4 + i][w * 16 + r] = nv;   // xi_s disjoint from h2
    }

    // h(l+1) epilogue: exact fp32 (same math as k_init's h)
    if (l + 1 < LAYERS) {
        __syncthreads();
        const float* W  = Wsm + (size_t)(l + 1) * DIM * 2 * SUB;
        const float* bs = bsm + (l + 1) * 2 * SUB;
        #pragma unroll
        for (int pp = 0; pp < 2; ++pp) {
            int pair = threadIdx.x + pp * 256;
            int nl = pair >> 5, j = pair & 31;
            float v = bs[j];
            const float* xr = &xi_s[nl][0];
            #pragma unroll 8
            for (int d = 0; d < DIM; ++d) v = fmaf(xr[d], W[d * 2 * SUB + j], v);
            int n = n0 + nl;
            if (j < SUB) si16[(size_t)n * SUB + j] = f2bf(v);
            else         mi_wr[(size_t)n * SUB + (j - SUB)] = f2bf(v);
        }
    }
}

extern "C" void kernel_launch(void* const* d_in, const int* in_sizes, int n_in,
                              void* d_out, int out_size, void* d_ws, size_t ws_size,
                              hipStream_t stream) {
    const int*   species = (const int*)  d_in[0];
    const int*   esrc    = (const int*)  d_in[1];
    const int*   edst    = (const int*)  d_in[2];
    const float* dist    = (const float*)d_in[3];
    const float* sw      = (const float*)d_in[4];
    const float* bo      = (const float*)d_in[5];
    const float* Wsp     = (const float*)d_in[6];
    const float* Wsm     = (const float*)d_in[7];
    const float* bsm     = (const float*)d_in[8];
    const float* w0      = (const float*)d_in[9];
    const float* b0      = (const float*)d_in[10];
    const float* w1      = (const float*)d_in[11];
    const float* b1      = (const float*)d_in[12];
    const float* w2      = (const float*)d_in[13];
    const float* b2      = (const float*)d_in[14];

    float* xi = (float*)d_out;   // N x 64 fp32, updated in place

    // ws layout: uT 48*E_PAD ush | mi16 2 x N*16 ush | si16 N*16 ush |
    //            w0f | w1f | w2f | rowptr
    unsigned short* uT    = (unsigned short*)d_ws;
    unsigned short* mi0   = uT + (size_t)48 * E_PAD;
    unsigned short* mi1   = mi0 + (size_t)N_NODES * SUB;
    unsigned short* si16  = mi1 + (size_t)N_NODES * SUB;
    short* w0f = (short*)(si16 + (size_t)N_NODES * SUB);
    short* w1f = w0f + (size_t)LAYERS * NKK * 2048;
    short* w2f = w1f + (size_t)LAYERS * 2 * 2048;
    int* rowptr = (int*)(w2f + (size_t)LAYERS * 2 * 2048);

    k_rowptr<<<(N_NODES + 1 + 255) / 256, 256, 0, stream>>>(esrc, rowptr);
    k_u<<<(E_PAD + 255) / 256, 256, 0, stream>>>(dist, sw, bo, uT);
    {
        int total = LAYERS * NKK * 2048 + 2 * LAYERS * 2 * 2048;
        k_packw<<<(total + 255) / 256, 256, 0, stream>>>(w0, w1, w2, w0f, w1f, w2f);
    }
    k_init<<<N_NODES / 8, 256, 0, stream>>>(species, Wsp, Wsm, bsm, xi, si16, mi0);

    for (int l = 0; l < LAYERS; ++l) {
        unsigned short* mi_rd = (l & 1) ? mi1 : mi0;
        unsigned short* mi_wr = (l & 1) ? mi0 : mi1;
        k_layer<<<N_NODES / 16, 256, 0, stream>>>(rowptr, edst, uT, mi_rd, mi_wr,
                                                  si16, w0f, b0, w1f, b1, w2f, b2,
                                                  Wsm, bsm, xi, l);
    }
}